// Round 4
// baseline (654.014 us; speedup 1.0000x reference)
//
#include <hip/hip_runtime.h>
#include <math.h>

// Problem constants
constexpr int B  = 8;
constexpr int C  = 256;   // Cin
constexpr int M  = 256;
constexpr int O  = 256;
constexpr int H  = 128;
constexpr int W  = 128;
constexpr int HW = H * W; // 16384
constexpr int K  = 128;   // top-k / kept channels

using f16   = _Float16;
using f16x2 = __attribute__((ext_vector_type(2))) _Float16;
using f16x8 = __attribute__((ext_vector_type(8))) _Float16;
using f32x4 = __attribute__((ext_vector_type(4))) float;

// Workspace layout (offsets in float units)
constexpr size_t WS_MEANX = 0;        // 2048
constexpr size_t WS_MASK  = 2048;     // 2048
constexpr size_t WS_G2    = 4096;     // 2048
constexpr size_t WS_OFF   = 6144;     // 48 (pad to 64)
constexpr size_t WS_WE3   = 6208;     // 9216
constexpr size_t WS_WE5   = 15424;    // 25600
constexpr size_t WS_WE7   = 41024;    // 50176
constexpr size_t WS_WT1G  = 91200;    // 65536 f16 (pw1_w fragment-linear)
constexpr size_t WS_WT2G  = 123968;   // 98304 f16 (pw_w[:, :384] fragment-linear)
constexpr size_t WS_SELH  = 173120;   // B*K*HW f16 = 8388608 float slots (33.5 MB)
// BIG region: union of xh (B*C*HW f16, dead after kCm) and yh2 (3*B*K*HW f16)
constexpr size_t WS_BIG   = 8561728;
// end = 33727552 floats = 134.91 MB (same proven footprint as before)

// ---------------------------------------------------------------------------
// Kernel T: fragment-linear f16 weight copies + zero meanx/gap2sum.
// ---------------------------------------------------------------------------
__global__ __launch_bounds__(256) void kT(const float* __restrict__ pw1_w,
                                          const float* __restrict__ pw_w,
                                          float* __restrict__ ws) {
  f16* wt1g = (f16*)(ws + WS_WT1G);
  f16* wt2g = (f16*)(ws + WS_WT2G);
  int t = blockIdx.x * 256 + threadIdx.x;
  if (t < 65536) {
    int ks = t >> 13, fr = (t >> 9) & 15, l = (t >> 3) & 63, j = t & 7;
    int o = fr * 16 + (l & 15);
    int c = ks * 32 + ((l >> 4) << 3) + j;
    wt1g[t] = (f16)pw1_w[o * C + c];
  }
  if (t < 98304) {
    int ks = t >> 13, fr = (t >> 9) & 15, l = (t >> 3) & 63, j = t & 7;
    int o = fr * 16 + (l & 15);
    int cc = ks * 32 + ((l >> 4) << 3) + j;
    wt2g[t] = (f16)pw_w[(size_t)o * 768 + cc];
  }
  if (t < 2048) {
    ws[WS_MEANX + t] = 0.f;
    ws[WS_G2 + t]    = 0.f;
  }
}

// ---------------------------------------------------------------------------
// Kernel AT: read x once; per-channel means (atomic partials) and xh = f16 x
// in octet-interleaved layout xh[((b*32+ko)*HW + p)*8 + j], k = 8ko+j.
// ---------------------------------------------------------------------------
__global__ __launch_bounds__(256) void kAT(const float* __restrict__ x,
                                           float* __restrict__ ws) {
  float* meanx = ws + WS_MEANX;
  f16* xh      = (f16*)(ws + WS_BIG);
  int b = blockIdx.z, ko = blockIdx.y, p0 = blockIdx.x * 256;
  __shared__ float sx[8][256];
  int t = threadIdx.x;
  int c8 = t >> 5, pg = t & 31;
  const float* xp = x + (size_t)(b * 256 + ko * 8 + c8) * HW + p0 + pg * 8;
  float4 v0 = ((const float4*)xp)[0];
  float4 v1 = ((const float4*)xp)[1];
  *(float4*)&sx[c8][pg * 8]     = v0;
  *(float4*)&sx[c8][pg * 8 + 4] = v1;
  float s = v0.x + v0.y + v0.z + v0.w + v1.x + v1.y + v1.z + v1.w;
#pragma unroll
  for (int off = 16; off > 0; off >>= 1) s += __shfl_xor(s, off, 32);
  if (pg == 0) atomicAdd(&meanx[b * 256 + ko * 8 + c8], s * (1.f / HW));
  __syncthreads();
  f16x8 o;
#pragma unroll
  for (int j = 0; j < 8; j++) o[j] = (f16)sx[j][t];
  *(f16x8*)&xh[((size_t)(b * 32 + ko) * HW + p0 + t) * 8] = o;
}

// ---------------------------------------------------------------------------
// Kernel B: per-batch block; exact fp32 scoring path (unchanged).
// ---------------------------------------------------------------------------
__global__ __launch_bounds__(256) void kB(const float* __restrict__ pw1_w,
                                          const float* __restrict__ pw1_b,
                                          const float* __restrict__ fc1_w,
                                          const float* __restrict__ fc1_b,
                                          const float* __restrict__ fc2_w,
                                          const float* __restrict__ fc2_b,
                                          float* __restrict__ ws) {
  int b = blockIdx.x;
  const float* meanx = ws + WS_MEANX + b * C;
  float* maskg = ws + WS_MASK;
  __shared__ float s_gap[M];
  __shared__ float s_hid[512];
  __shared__ float s_sc[M];
  int t = threadIdx.x;
  int lane = t & 63, wv = t >> 6;

  float4 mx = ((const float4*)meanx)[lane];
  for (int o0 = wv * 64; o0 < wv * 64 + 64; o0 += 4) {
    float s[4];
#pragma unroll
    for (int j = 0; j < 4; j++) {
      float4 w = ((const float4*)(pw1_w + (size_t)(o0 + j) * C))[lane];
      s[j] = mx.x * w.x + mx.y * w.y + mx.z * w.z + mx.w * w.w;
    }
#pragma unroll
    for (int off = 32; off > 0; off >>= 1)
#pragma unroll
      for (int j = 0; j < 4; j++) s[j] += __shfl_xor(s[j], off, 64);
    if (lane == 0) {
#pragma unroll
      for (int j = 0; j < 4; j++) s_gap[o0 + j] = s[j] + pw1_b[o0 + j];
    }
  }
  __syncthreads();

  float4 g4 = ((const float4*)s_gap)[lane];
  for (int j0 = wv * 128; j0 < wv * 128 + 128; j0 += 4) {
    float s[4];
#pragma unroll
    for (int j = 0; j < 4; j++) {
      float4 w = ((const float4*)(fc1_w + (size_t)(j0 + j) * M))[lane];
      s[j] = g4.x * w.x + g4.y * w.y + g4.z * w.z + g4.w * w.w;
    }
#pragma unroll
    for (int off = 32; off > 0; off >>= 1)
#pragma unroll
      for (int j = 0; j < 4; j++) s[j] += __shfl_xor(s[j], off, 64);
    if (lane == 0) {
#pragma unroll
      for (int j = 0; j < 4; j++) {
        float v = s[j] + fc1_b[j0 + j];
        s_hid[j0 + j] = v > 0.f ? v : 0.f;
      }
    }
  }
  __syncthreads();

  float4 h0 = ((const float4*)s_hid)[lane];
  float4 h1 = ((const float4*)s_hid)[lane + 64];
  for (int o0 = wv * 64; o0 < wv * 64 + 64; o0 += 4) {
    float s[4];
#pragma unroll
    for (int j = 0; j < 4; j++) {
      const float4* wr = (const float4*)(fc2_w + (size_t)(o0 + j) * 512);
      float4 w0 = wr[lane];
      float4 w1 = wr[lane + 64];
      s[j] = h0.x * w0.x + h0.y * w0.y + h0.z * w0.z + h0.w * w0.w +
             h1.x * w1.x + h1.y * w1.y + h1.z * w1.z + h1.w * w1.w;
    }
#pragma unroll
    for (int off = 32; off > 0; off >>= 1)
#pragma unroll
      for (int j = 0; j < 4; j++) s[j] += __shfl_xor(s[j], off, 64);
    if (lane == 0) {
#pragma unroll
      for (int j = 0; j < 4; j++) {
        float v = s[j] + fc2_b[o0 + j];
        s_sc[o0 + j] = 1.f / (1.f + expf(-v));
      }
    }
  }
  __syncthreads();

  {
    int j = t;
    float sj = s_sc[j];
    int cnt = 0;
    for (int m = 0; m < M; m++) {
      float sm = s_sc[m];
      cnt += (sm > sj) || (sm == sj && m < j);
    }
    maskg[b * M + j] = (cnt < K) ? 1.f : 0.f;
  }
}

// ---------------------------------------------------------------------------
// Kernel Cm: h = relu(pw1(x)) via f16 MFMA. Barrier-free, LDS-free.
// 32-px blocks (acc[4][2], ~half the VGPRs) for 2x occupancy; A-operand is
// L2-resident so extra blocks add no HBM traffic.
// ---------------------------------------------------------------------------
__global__ __launch_bounds__(256, 4) void kCm(const float* __restrict__ pw1_b,
                                              float* __restrict__ ws) {
  const f16* wt1g = (const f16*)(ws + WS_WT1G);
  const f16* xh   = (const f16*)(ws + WS_BIG);
  float* gap2sum  = ws + WS_G2;
  f16* selh       = (f16*)(ws + WS_SELH);
  int b  = blockIdx.z;
  int p0 = blockIdx.x * 32;

  int t = threadIdx.x, l = t & 63, w = t >> 6;
  int q = l >> 4, n = l & 15;

  f32x4 acc[4][2];
#pragma unroll
  for (int i = 0; i < 4; i++)
#pragma unroll
    for (int j = 0; j < 2; j++)
#pragma unroll
      for (int r = 0; r < 4; r++) acc[i][j][r] = 0.f;

  const f16* bbase = xh + (size_t)(b * 32 + q) * (HW * 8) + (size_t)(p0 + n) * 8;
  const f16* abase = wt1g + (size_t)(w * 4) * 512 + (size_t)l * 8;

#pragma unroll 2
  for (int ks = 0; ks < 8; ks++) {
    f16x8 afr[4], bfr[2];
#pragma unroll
    for (int mt = 0; mt < 4; mt++)
      afr[mt] = *(const f16x8*)(abase + (size_t)(ks * 16 + mt) * 512);
#pragma unroll
    for (int nt = 0; nt < 2; nt++)
      bfr[nt] = *(const f16x8*)(bbase + (size_t)ks * (4 * HW * 8) + nt * 128);
#pragma unroll
    for (int mt = 0; mt < 4; mt++)
#pragma unroll
      for (int nt = 0; nt < 2; nt++)
        acc[mt][nt] = __builtin_amdgcn_mfma_f32_16x16x32_f16(afr[mt], bfr[nt],
                                                             acc[mt][nt], 0, 0, 0);
  }

  // Epilogue: bias + relu; sel f16 store (o<128); gap2sum partial sums
#pragma unroll
  for (int mt = 0; mt < 4; mt++) {
    float rsum[4] = {0.f, 0.f, 0.f, 0.f};
    int obase = w * 64 + mt * 16 + q * 4;
    float bias[4];
#pragma unroll
    for (int r = 0; r < 4; r++) bias[r] = pw1_b[obase + r];
#pragma unroll
    for (int nt = 0; nt < 2; nt++) {
      int p = p0 + nt * 16 + n;
#pragma unroll
      for (int r = 0; r < 4; r++) {
        float h = acc[mt][nt][r] + bias[r];
        h = h > 0.f ? h : 0.f;
        rsum[r] += h;
        int o = obase + r;
        if (o < K) selh[((size_t)(b * K + o)) * HW + p] = (f16)h;
      }
    }
#pragma unroll
    for (int off = 1; off < 16; off <<= 1)
#pragma unroll
      for (int r = 0; r < 4; r++) rsum[r] += __shfl_xor(rsum[r], off, 64);
    if (n == 0) {
#pragma unroll
      for (int r = 0; r < 4; r++)
        atomicAdd(&gap2sum[b * M + obase + r], rsum[r]);
    }
  }
}

// ---------------------------------------------------------------------------
// Kernel D1 (1 block): offsets from gap2; emit per-(b,branch) scale/shift.
// ---------------------------------------------------------------------------
__global__ __launch_bounds__(256) void kD1(const float* __restrict__ off_w,
                                           const float* __restrict__ off_b,
                                           float* __restrict__ ws) {
  const float* gap2sum = ws + WS_G2;
  float* offv = ws + WS_OFF;  // [0..23]=scale(b*3+i), [24..47]=shift
  __shared__ float s_off[48];
  int t = threadIdx.x;
  int lane = t & 63, wv = t >> 6;
  for (int id = wv; id < 48; id += 4) {
    int b = id / 6, j = id % 6;
    float4 g = ((const float4*)(gap2sum + b * M))[lane];
    float4 w = ((const float4*)(off_w + (size_t)j * M))[lane];
    float s = (g.x * w.x + g.y * w.y + g.z * w.z + g.w * w.w) * (1.f / HW);
#pragma unroll
    for (int off = 32; off > 0; off >>= 1) s += __shfl_xor(s, off, 64);
    if (lane == 0) s_off[id] = tanhf(s + off_b[j]);
  }
  __syncthreads();
  if (t < 24) {
    int b = t / 3, i = t % 3;
    offv[t]      = 1.f + 1.f / (1.f + expf(-s_off[b * 6 + 2 * i]));
    offv[24 + t] = tanhf(s_off[b * 6 + 2 * i + 1]);
  }
}

// ---------------------------------------------------------------------------
// Kernel D2: effective depthwise weights, with top-k mask folded in.
// ---------------------------------------------------------------------------
__global__ __launch_bounds__(256) void kD2(const float* __restrict__ dw3,
                                           const float* __restrict__ dw5,
                                           const float* __restrict__ dw7,
                                           float* __restrict__ ws) {
  const float* offv  = ws + WS_OFF;
  const float* maskg = ws + WS_MASK;
  float* wE3 = ws + WS_WE3;
  float* wE5 = ws + WS_WE5;
  float* wE7 = ws + WS_WE7;
  int tid = blockIdx.x * 256 + threadIdx.x;
  int stride = gridDim.x * 256;
  for (int i = tid; i < B * K * 9; i += stride) {
    int b = i / (K * 9), rem = i % (K * 9), c = rem / 9;
    wE3[i] = (dw3[rem] * offv[b * 3 + 0] + offv[24 + b * 3 + 0]) * maskg[b * M + c];
  }
  for (int i = tid; i < B * K * 25; i += stride) {
    int b = i / (K * 25), rem = i % (K * 25), c = rem / 25;
    wE5[i] = (dw5[rem] * offv[b * 3 + 1] + offv[24 + b * 3 + 1]) * maskg[b * M + c];
  }
  for (int i = tid; i < B * K * 49; i += stride) {
    int b = i / (K * 49), rem = i % (K * 49), c = rem / 49;
    wE7[i] = (dw7[rem] * offv[b * 3 + 2] + offv[24 + b * 3 + 2]) * maskg[b * M + c];
  }
}

// ---------------------------------------------------------------------------
// Kernel Em: merged depthwise conv. f16 halo in LDS; compute = f16x2 LDS
// reads -> cvt -> fp32 fma (the proven-fast R2 form). NEW: vectorized fill —
// halo row origin c0-8 is 8-aligned, so the fill is pure f16x8 chunks
// (6.9 vector loads/thread vs 49.5 scalar). Plane stride 1768 f16
// (884 dw % 32 = 20 -> 8 ch hit 8 distinct bank quads; conflict-free).
// Block: 256 thr = 8 ch x 32 col-pairs; 16 rows x 64 cols x 8 ch per block.
// ---------------------------------------------------------------------------
__global__ __launch_bounds__(256) void kEm(const float* __restrict__ ws_ro,
                                           float* __restrict__ ws) {
  constexpr int SP = 1768;  // f16 per channel plane (22 rows x 80 + pad)
  __shared__ f16 sm[8 * SP];  // 28288 B
  const f16* selh = (const f16*)(ws_ro + WS_SELH);
  f16* yh2        = (f16*)(ws + WS_BIG);
  int bx = blockIdx.x;
  int slab = bx >> 1, chalf = bx & 1;
  int ko = blockIdx.y, b = blockIdx.z;
  int r0 = slab * 16, c0 = chalf * 64;

  // Fill: per (ch, row rr of 22, chunk of 10): one f16x8 from global or zeros.
  // LDS row col L corresponds to global col c0 - 8 + L.
  for (int i = threadIdx.x; i < 8 * 220; i += 256) {
    int chn = i / 220, rem = i - chn * 220;
    int rr = rem / 10, chunk = rem - rr * 10;
    int gy = r0 - 3 + rr, g0 = c0 - 8 + chunk * 8;
    f16x8 v = {};
    if (gy >= 0 && gy < H && g0 >= 0 && g0 < W)
      v = *(const f16x8*)&selh[(size_t)(b * 128 + ko * 8 + chn) * HW + gy * W + g0];
    *(f16x8*)&sm[chn * SP + rr * 80 + chunk * 8] = v;
  }
  __syncthreads();

  int t = threadIdx.x;
  int ch = t & 7, cp = t >> 3;  // channel 0..7, col-pair 0..31
  int cglob = c0 + cp * 2;

  // Tap f16-index within the vv window: even col: (8-P)+dx-2*SOFF,
  // odd col: (9-P)+dx-2*SOFF. (KS,NW,SOFF) = (3,3,3),(5,3,3),(7,5,2).
#define CONV_BRANCH(KS, BR, WSOFF, NW, SOFF)                                   \
  {                                                                            \
    constexpr int P = (KS - 1) / 2;                                            \
    const float* wp = ws_ro + WSOFF + (size_t)(b * 128 + ko * 8 + ch) * (KS*KS); \
    float w[KS * KS];                                                          \
    _Pragma("unroll") for (int i = 0; i < KS * KS; i++) w[i] = wp[i];          \
    float a0[16], a1[16];                                                      \
    _Pragma("unroll") for (int r = 0; r < 16; r++) { a0[r] = 0.f; a1[r] = 0.f; } \
    _Pragma("unroll") for (int iy = 0; iy < 16 + 2 * P; iy++) {                \
      int hr = iy + (3 - P);                                                   \
      const f16x2* rowp = (const f16x2*)(sm + ch * SP + hr * 80);              \
      float vv[2 * NW];                                                        \
      _Pragma("unroll") for (int u = 0; u < NW; u++) {                         \
        f16x2 pr = rowp[cp + SOFF + u];                                        \
        vv[2 * u]     = (float)pr[0];                                          \
        vv[2 * u + 1] = (float)pr[1];                                          \
      }                                                                        \
      _Pragma("unroll") for (int rr = 0; rr < 16; rr++) {                      \
        int dy = iy - rr;                                                      \
        if (dy >= 0 && dy < KS) {                                              \
          _Pragma("unroll") for (int dx = 0; dx < KS; dx++) {                  \
            int m = (8 - P) + dx - 2 * SOFF;                                   \
            a0[rr] += vv[m]     * w[dy * KS + dx];                             \
            a1[rr] += vv[m + 1] * w[dy * KS + dx];                             \
          }                                                                    \
        }                                                                      \
      }                                                                        \
    }                                                                          \
    f16* op = yh2 + (size_t)(b * 48 + BR * 16 + ko) * HW * 8;                  \
    _Pragma("unroll") for (int rr = 0; rr < 16; rr++) {                        \
      size_t pa = ((size_t)(r0 + rr) * W + cglob) * 8 + ch;                    \
      op[pa]     = (f16)a0[rr];                                                \
      op[pa + 8] = (f16)a1[rr];                                                \
    }                                                                          \
  }

  CONV_BRANCH(3, 0, WS_WE3, 3, 3)
  CONV_BRANCH(5, 1, WS_WE5, 3, 3)
  CONV_BRANCH(7, 2, WS_WE7, 5, 2)
#undef CONV_BRANCH
}

// ---------------------------------------------------------------------------
// Kernel Fm: merged final pointwise, f16 MFMA, K=384. Barrier-free, LDS-free.
// 32-px blocks for 2x occupancy (A is L2-resident; no extra HBM traffic).
// ---------------------------------------------------------------------------
__global__ __launch_bounds__(256, 4) void kFm(const float* __restrict__ x,
                                              const float* __restrict__ pw_b,
                                              const float* __restrict__ ws,
                                              float* __restrict__ out) {
  const f16* wt2g = (const f16*)(ws + WS_WT2G);
  const f16* yh2  = (const f16*)(ws + WS_BIG);
  int b  = blockIdx.z;
  int p0 = blockIdx.x * 32;

  int t = threadIdx.x, l = t & 63, w = t >> 6;
  int q = l >> 4, n = l & 15;

  f32x4 acc[4][2];
#pragma unroll
  for (int i = 0; i < 4; i++)
#pragma unroll
    for (int j = 0; j < 2; j++)
#pragma unroll
      for (int r = 0; r < 4; r++) acc[i][j][r] = 0.f;

  const f16* bbase = yh2 + (size_t)(b * 48 + q) * (HW * 8) + (size_t)(p0 + n) * 8;
  const f16* abase = wt2g + (size_t)(w * 4) * 512 + (size_t)l * 8;

#pragma unroll 2
  for (int ks = 0; ks < 12; ks++) {
    f16x8 afr[4], bfr[2];
#pragma unroll
    for (int mt = 0; mt < 4; mt++)
      afr[mt] = *(const f16x8*)(abase + (size_t)(ks * 16 + mt) * 512);
#pragma unroll
    for (int nt = 0; nt < 2; nt++)
      bfr[nt] = *(const f16x8*)(bbase + (size_t)ks * (4 * HW * 8) + nt * 128);
#pragma unroll
    for (int mt = 0; mt < 4; mt++)
#pragma unroll
      for (int nt = 0; nt < 2; nt++)
        acc[mt][nt] = __builtin_amdgcn_mfma_f32_16x16x32_f16(afr[mt], bfr[nt],
                                                             acc[mt][nt], 0, 0, 0);
  }

#pragma unroll
  for (int mt = 0; mt < 4; mt++) {
    int obase = w * 64 + mt * 16 + q * 4;
    float bias[4];
#pragma unroll
    for (int r = 0; r < 4; r++) bias[r] = pw_b[obase + r];
#pragma unroll
    for (int nt = 0; nt < 2; nt++) {
      int p = p0 + nt * 16 + n;
#pragma unroll
      for (int r = 0; r < 4; r++) {
        size_t idx = ((size_t)b * O + obase + r) * HW + p;
        out[idx] = acc[mt][nt][r] + bias[r] + x[idx];
      }
    }
  }
}

// ---------------------------------------------------------------------------
extern "C" void kernel_launch(void* const* d_in, const int* in_sizes, int n_in,
                              void* d_out, int out_size, void* d_ws, size_t ws_size,
                              hipStream_t stream) {
  const float* x     = (const float*)d_in[0];
  const float* pw1_w = (const float*)d_in[1];
  const float* pw1_b = (const float*)d_in[2];
  const float* fc1_w = (const float*)d_in[3];
  const float* fc1_b = (const float*)d_in[4];
  const float* fc2_w = (const float*)d_in[5];
  const float* fc2_b = (const float*)d_in[6];
  const float* off_w = (const float*)d_in[7];
  const float* off_b = (const float*)d_in[8];
  const float* dw3   = (const float*)d_in[9];
  const float* dw5   = (const float*)d_in[10];
  const float* dw7   = (const float*)d_in[11];
  const float* pw_w  = (const float*)d_in[12];
  const float* pw_b  = (const float*)d_in[13];
  float* out = (float*)d_out;
  float* ws  = (float*)d_ws;

  kT<<<384, 256, 0, stream>>>(pw1_w, pw_w, ws);
  kAT<<<dim3(HW / 256, 32, B), 256, 0, stream>>>(x, ws);
  kB<<<B, 256, 0, stream>>>(pw1_w, pw1_b, fc1_w, fc1_b, fc2_w, fc2_b, ws);
  kCm<<<dim3(HW / 32, 1, B), 256, 0, stream>>>(pw1_b, ws);
  kD1<<<1, 256, 0, stream>>>(off_w, off_b, ws);
  kD2<<<84, 256, 0, stream>>>(dw3, dw5, dw7, ws);
  kEm<<<dim3(16, 16, B), 256, 0, stream>>>(ws, ws);
  kFm<<<dim3(HW / 32, 1, B), 256, 0, stream>>>(x, pw_b, ws, out);
}

// Round 5
// 573.914 us; speedup vs baseline: 1.1396x; 1.1396x over previous
//
#include <hip/hip_runtime.h>
#include <math.h>

// Problem constants
constexpr int B  = 8;
constexpr int C  = 256;   // Cin
constexpr int M  = 256;
constexpr int O  = 256;
constexpr int H  = 128;
constexpr int W  = 128;
constexpr int HW = H * W; // 16384
constexpr int K  = 128;   // top-k / kept channels

using f16   = _Float16;
using f16x2 = __attribute__((ext_vector_type(2))) _Float16;
using f16x8 = __attribute__((ext_vector_type(8))) _Float16;
using f32x4 = __attribute__((ext_vector_type(4))) float;

// Workspace layout (offsets in float units)
constexpr size_t WS_MEANX = 0;        // 2048
constexpr size_t WS_MASK  = 2048;     // 2048
constexpr size_t WS_G2    = 4096;     // 2048
constexpr size_t WS_OFF   = 6144;     // 48 (pad to 64)
constexpr size_t WS_WE3   = 6208;     // 9216
constexpr size_t WS_WE5   = 15424;    // 25600
constexpr size_t WS_WE7   = 41024;    // 50176
constexpr size_t WS_WT1G  = 91200;    // 65536 f16 (pw1_w fragment-linear)
constexpr size_t WS_WT2G  = 123968;   // 98304 f16 (pw_w[:, :384] fragment-linear)
constexpr size_t WS_SELH  = 173120;   // B*K*HW f16 = 8388608 float slots (33.5 MB)
// BIG region: union of xh (B*C*HW f16, dead after kCm) and yh2 (3*B*K*HW f16)
constexpr size_t WS_BIG   = 8561728;
// end = 33727552 floats = 134.91 MB (same proven footprint as before)

// ---------------------------------------------------------------------------
// Kernel T: fragment-linear f16 weight copies + zero meanx/gap2sum.
// ---------------------------------------------------------------------------
__global__ __launch_bounds__(256) void kT(const float* __restrict__ pw1_w,
                                          const float* __restrict__ pw_w,
                                          float* __restrict__ ws) {
  f16* wt1g = (f16*)(ws + WS_WT1G);
  f16* wt2g = (f16*)(ws + WS_WT2G);
  int t = blockIdx.x * 256 + threadIdx.x;
  if (t < 65536) {
    int ks = t >> 13, fr = (t >> 9) & 15, l = (t >> 3) & 63, j = t & 7;
    int o = fr * 16 + (l & 15);
    int c = ks * 32 + ((l >> 4) << 3) + j;
    wt1g[t] = (f16)pw1_w[o * C + c];
  }
  if (t < 98304) {
    int ks = t >> 13, fr = (t >> 9) & 15, l = (t >> 3) & 63, j = t & 7;
    int o = fr * 16 + (l & 15);
    int cc = ks * 32 + ((l >> 4) << 3) + j;
    wt2g[t] = (f16)pw_w[(size_t)o * 768 + cc];
  }
  if (t < 2048) {
    ws[WS_MEANX + t] = 0.f;
    ws[WS_G2 + t]    = 0.f;
  }
}

// ---------------------------------------------------------------------------
// Kernel AT: read x once; per-channel means (atomic partials) and xh = f16 x
// in octet-interleaved layout xh[((b*32+ko)*HW + p)*8 + j], k = 8ko+j.
// ---------------------------------------------------------------------------
__global__ __launch_bounds__(256) void kAT(const float* __restrict__ x,
                                           float* __restrict__ ws) {
  float* meanx = ws + WS_MEANX;
  f16* xh      = (f16*)(ws + WS_BIG);
  int b = blockIdx.z, ko = blockIdx.y, p0 = blockIdx.x * 256;
  __shared__ float sx[8][256];
  int t = threadIdx.x;
  int c8 = t >> 5, pg = t & 31;
  const float* xp = x + (size_t)(b * 256 + ko * 8 + c8) * HW + p0 + pg * 8;
  float4 v0 = ((const float4*)xp)[0];
  float4 v1 = ((const float4*)xp)[1];
  *(float4*)&sx[c8][pg * 8]     = v0;
  *(float4*)&sx[c8][pg * 8 + 4] = v1;
  float s = v0.x + v0.y + v0.z + v0.w + v1.x + v1.y + v1.z + v1.w;
#pragma unroll
  for (int off = 16; off > 0; off >>= 1) s += __shfl_xor(s, off, 32);
  if (pg == 0) atomicAdd(&meanx[b * 256 + ko * 8 + c8], s * (1.f / HW));
  __syncthreads();
  f16x8 o;
#pragma unroll
  for (int j = 0; j < 8; j++) o[j] = (f16)sx[j][t];
  *(f16x8*)&xh[((size_t)(b * 32 + ko) * HW + p0 + t) * 8] = o;
}

// ---------------------------------------------------------------------------
// Kernel B: per-batch block; exact fp32 scoring path (unchanged).
// ---------------------------------------------------------------------------
__global__ __launch_bounds__(256) void kB(const float* __restrict__ pw1_w,
                                          const float* __restrict__ pw1_b,
                                          const float* __restrict__ fc1_w,
                                          const float* __restrict__ fc1_b,
                                          const float* __restrict__ fc2_w,
                                          const float* __restrict__ fc2_b,
                                          float* __restrict__ ws) {
  int b = blockIdx.x;
  const float* meanx = ws + WS_MEANX + b * C;
  float* maskg = ws + WS_MASK;
  __shared__ float s_gap[M];
  __shared__ float s_hid[512];
  __shared__ float s_sc[M];
  int t = threadIdx.x;
  int lane = t & 63, wv = t >> 6;

  float4 mx = ((const float4*)meanx)[lane];
  for (int o0 = wv * 64; o0 < wv * 64 + 64; o0 += 4) {
    float s[4];
#pragma unroll
    for (int j = 0; j < 4; j++) {
      float4 w = ((const float4*)(pw1_w + (size_t)(o0 + j) * C))[lane];
      s[j] = mx.x * w.x + mx.y * w.y + mx.z * w.z + mx.w * w.w;
    }
#pragma unroll
    for (int off = 32; off > 0; off >>= 1)
#pragma unroll
      for (int j = 0; j < 4; j++) s[j] += __shfl_xor(s[j], off, 64);
    if (lane == 0) {
#pragma unroll
      for (int j = 0; j < 4; j++) s_gap[o0 + j] = s[j] + pw1_b[o0 + j];
    }
  }
  __syncthreads();

  float4 g4 = ((const float4*)s_gap)[lane];
  for (int j0 = wv * 128; j0 < wv * 128 + 128; j0 += 4) {
    float s[4];
#pragma unroll
    for (int j = 0; j < 4; j++) {
      float4 w = ((const float4*)(fc1_w + (size_t)(j0 + j) * M))[lane];
      s[j] = g4.x * w.x + g4.y * w.y + g4.z * w.z + g4.w * w.w;
    }
#pragma unroll
    for (int off = 32; off > 0; off >>= 1)
#pragma unroll
      for (int j = 0; j < 4; j++) s[j] += __shfl_xor(s[j], off, 64);
    if (lane == 0) {
#pragma unroll
      for (int j = 0; j < 4; j++) {
        float v = s[j] + fc1_b[j0 + j];
        s_hid[j0 + j] = v > 0.f ? v : 0.f;
      }
    }
  }
  __syncthreads();

  float4 h0 = ((const float4*)s_hid)[lane];
  float4 h1 = ((const float4*)s_hid)[lane + 64];
  for (int o0 = wv * 64; o0 < wv * 64 + 64; o0 += 4) {
    float s[4];
#pragma unroll
    for (int j = 0; j < 4; j++) {
      const float4* wr = (const float4*)(fc2_w + (size_t)(o0 + j) * 512);
      float4 w0 = wr[lane];
      float4 w1 = wr[lane + 64];
      s[j] = h0.x * w0.x + h0.y * w0.y + h0.z * w0.z + h0.w * w0.w +
             h1.x * w1.x + h1.y * w1.y + h1.z * w1.z + h1.w * w1.w;
    }
#pragma unroll
    for (int off = 32; off > 0; off >>= 1)
#pragma unroll
      for (int j = 0; j < 4; j++) s[j] += __shfl_xor(s[j], off, 64);
    if (lane == 0) {
#pragma unroll
      for (int j = 0; j < 4; j++) {
        float v = s[j] + fc2_b[o0 + j];
        s_sc[o0 + j] = 1.f / (1.f + expf(-v));
      }
    }
  }
  __syncthreads();

  {
    int j = t;
    float sj = s_sc[j];
    int cnt = 0;
    for (int m = 0; m < M; m++) {
      float sm = s_sc[m];
      cnt += (sm > sj) || (sm == sj && m < j);
    }
    maskg[b * M + j] = (cnt < K) ? 1.f : 0.f;
  }
}

// ---------------------------------------------------------------------------
// Kernel Cm: h = relu(pw1(x)) via f16 MFMA. Barrier-free, LDS-free.
// 64-px blocks (proven best: 16 MFMA per 8-load batch hides latency;
// 32-px variant regressed — R4 post-mortem).
// ---------------------------------------------------------------------------
__global__ __launch_bounds__(256) void kCm(const float* __restrict__ pw1_b,
                                           float* __restrict__ ws) {
  const f16* wt1g = (const f16*)(ws + WS_WT1G);
  const f16* xh   = (const f16*)(ws + WS_BIG);
  float* gap2sum  = ws + WS_G2;
  f16* selh       = (f16*)(ws + WS_SELH);
  int b  = blockIdx.z;
  int p0 = blockIdx.x * 64;

  int t = threadIdx.x, l = t & 63, w = t >> 6;
  int q = l >> 4, n = l & 15;

  f32x4 acc[4][4];
#pragma unroll
  for (int i = 0; i < 4; i++)
#pragma unroll
    for (int j = 0; j < 4; j++)
#pragma unroll
      for (int r = 0; r < 4; r++) acc[i][j][r] = 0.f;

  const f16* bbase = xh + (size_t)(b * 32 + q) * (HW * 8) + (size_t)(p0 + n) * 8;
  const f16* abase = wt1g + (size_t)(w * 4) * 512 + (size_t)l * 8;

#pragma unroll 2
  for (int ks = 0; ks < 8; ks++) {
    f16x8 afr[4], bfr[4];
#pragma unroll
    for (int mt = 0; mt < 4; mt++)
      afr[mt] = *(const f16x8*)(abase + (size_t)(ks * 16 + mt) * 512);
#pragma unroll
    for (int nt = 0; nt < 4; nt++)
      bfr[nt] = *(const f16x8*)(bbase + (size_t)ks * (4 * HW * 8) + nt * 128);
#pragma unroll
    for (int mt = 0; mt < 4; mt++)
#pragma unroll
      for (int nt = 0; nt < 4; nt++)
        acc[mt][nt] = __builtin_amdgcn_mfma_f32_16x16x32_f16(afr[mt], bfr[nt],
                                                             acc[mt][nt], 0, 0, 0);
  }

  // Epilogue: bias + relu; sel f16 store (o<128); gap2sum partial sums
#pragma unroll
  for (int mt = 0; mt < 4; mt++) {
    float rsum[4] = {0.f, 0.f, 0.f, 0.f};
    int obase = w * 64 + mt * 16 + q * 4;
    float bias[4];
#pragma unroll
    for (int r = 0; r < 4; r++) bias[r] = pw1_b[obase + r];
#pragma unroll
    for (int nt = 0; nt < 4; nt++) {
      int p = p0 + nt * 16 + n;
#pragma unroll
      for (int r = 0; r < 4; r++) {
        float h = acc[mt][nt][r] + bias[r];
        h = h > 0.f ? h : 0.f;
        rsum[r] += h;
        int o = obase + r;
        if (o < K) selh[((size_t)(b * K + o)) * HW + p] = (f16)h;
      }
    }
#pragma unroll
    for (int off = 1; off < 16; off <<= 1)
#pragma unroll
      for (int r = 0; r < 4; r++) rsum[r] += __shfl_xor(rsum[r], off, 64);
    if (n == 0) {
#pragma unroll
      for (int r = 0; r < 4; r++)
        atomicAdd(&gap2sum[b * M + obase + r], rsum[r]);
    }
  }
}

// ---------------------------------------------------------------------------
// Kernel D1 (1 block): offsets from gap2; emit per-(b,branch) scale/shift.
// ---------------------------------------------------------------------------
__global__ __launch_bounds__(256) void kD1(const float* __restrict__ off_w,
                                           const float* __restrict__ off_b,
                                           float* __restrict__ ws) {
  const float* gap2sum = ws + WS_G2;
  float* offv = ws + WS_OFF;  // [0..23]=scale(b*3+i), [24..47]=shift
  __shared__ float s_off[48];
  int t = threadIdx.x;
  int lane = t & 63, wv = t >> 6;
  for (int id = wv; id < 48; id += 4) {
    int b = id / 6, j = id % 6;
    float4 g = ((const float4*)(gap2sum + b * M))[lane];
    float4 w = ((const float4*)(off_w + (size_t)j * M))[lane];
    float s = (g.x * w.x + g.y * w.y + g.z * w.z + g.w * w.w) * (1.f / HW);
#pragma unroll
    for (int off = 32; off > 0; off >>= 1) s += __shfl_xor(s, off, 64);
    if (lane == 0) s_off[id] = tanhf(s + off_b[j]);
  }
  __syncthreads();
  if (t < 24) {
    int b = t / 3, i = t % 3;
    offv[t]      = 1.f + 1.f / (1.f + expf(-s_off[b * 6 + 2 * i]));
    offv[24 + t] = tanhf(s_off[b * 6 + 2 * i + 1]);
  }
}

// ---------------------------------------------------------------------------
// Kernel D2: effective depthwise weights, with top-k mask folded in.
// ---------------------------------------------------------------------------
__global__ __launch_bounds__(256) void kD2(const float* __restrict__ dw3,
                                           const float* __restrict__ dw5,
                                           const float* __restrict__ dw7,
                                           float* __restrict__ ws) {
  const float* offv  = ws + WS_OFF;
  const float* maskg = ws + WS_MASK;
  float* wE3 = ws + WS_WE3;
  float* wE5 = ws + WS_WE5;
  float* wE7 = ws + WS_WE7;
  int tid = blockIdx.x * 256 + threadIdx.x;
  int stride = gridDim.x * 256;
  for (int i = tid; i < B * K * 9; i += stride) {
    int b = i / (K * 9), rem = i % (K * 9), c = rem / 9;
    wE3[i] = (dw3[rem] * offv[b * 3 + 0] + offv[24 + b * 3 + 0]) * maskg[b * M + c];
  }
  for (int i = tid; i < B * K * 25; i += stride) {
    int b = i / (K * 25), rem = i % (K * 25), c = rem / 25;
    wE5[i] = (dw5[rem] * offv[b * 3 + 1] + offv[24 + b * 3 + 1]) * maskg[b * M + c];
  }
  for (int i = tid; i < B * K * 49; i += stride) {
    int b = i / (K * 49), rem = i % (K * 49), c = rem / 49;
    wE7[i] = (dw7[rem] * offv[b * 3 + 2] + offv[24 + b * 3 + 2]) * maskg[b * M + c];
  }
}

// ---------------------------------------------------------------------------
// Kernel Em: merged depthwise conv. f16 halo in LDS; compute = f16x2 LDS
// reads -> cvt -> fp32 fma. Vectorized fill: halo row origin c0-8 is
// 8-aligned -> pure f16x8 chunks. Plane stride 1768 f16 (884 dw % 32 = 20).
// Block: 256 thr = 8 ch x 32 col-pairs; 16 rows x 64 cols x 8 ch per block.
// ---------------------------------------------------------------------------
__global__ __launch_bounds__(256) void kEm(const float* __restrict__ ws_ro,
                                           float* __restrict__ ws) {
  constexpr int SP = 1768;  // f16 per channel plane (22 rows x 80 + pad)
  __shared__ f16 sm[8 * SP];  // 28288 B
  const f16* selh = (const f16*)(ws_ro + WS_SELH);
  f16* yh2        = (f16*)(ws + WS_BIG);
  int bx = blockIdx.x;
  int slab = bx >> 1, chalf = bx & 1;
  int ko = blockIdx.y, b = blockIdx.z;
  int r0 = slab * 16, c0 = chalf * 64;

  // Fill: per (ch, row rr of 22, chunk of 10): one f16x8 from global or zeros.
  // LDS row col L corresponds to global col c0 - 8 + L.
  for (int i = threadIdx.x; i < 8 * 220; i += 256) {
    int chn = i / 220, rem = i - chn * 220;
    int rr = rem / 10, chunk = rem - rr * 10;
    int gy = r0 - 3 + rr, g0 = c0 - 8 + chunk * 8;
    f16x8 v = {};
    if (gy >= 0 && gy < H && g0 >= 0 && g0 < W)
      v = *(const f16x8*)&selh[(size_t)(b * 128 + ko * 8 + chn) * HW + gy * W + g0];
    *(f16x8*)&sm[chn * SP + rr * 80 + chunk * 8] = v;
  }
  __syncthreads();

  int t = threadIdx.x;
  int ch = t & 7, cp = t >> 3;  // channel 0..7, col-pair 0..31
  int cglob = c0 + cp * 2;

  // Tap f16-index within the vv window: even col: (8-P)+dx-2*SOFF,
  // odd col: (9-P)+dx-2*SOFF. (KS,NW,SOFF) = (3,3,3),(5,3,3),(7,5,2).
#define CONV_BRANCH(KS, BR, WSOFF, NW, SOFF)                                   \
  {                                                                            \
    constexpr int P = (KS - 1) / 2;                                            \
    const float* wp = ws_ro + WSOFF + (size_t)(b * 128 + ko * 8 + ch) * (KS*KS); \
    float w[KS * KS];                                                          \
    _Pragma("unroll") for (int i = 0; i < KS * KS; i++) w[i] = wp[i];          \
    float a0[16], a1[16];                                                      \
    _Pragma("unroll") for (int r = 0; r < 16; r++) { a0[r] = 0.f; a1[r] = 0.f; } \
    _Pragma("unroll") for (int iy = 0; iy < 16 + 2 * P; iy++) {                \
      int hr = iy + (3 - P);                                                   \
      const f16x2* rowp = (const f16x2*)(sm + ch * SP + hr * 80);              \
      float vv[2 * NW];                                                        \
      _Pragma("unroll") for (int u = 0; u < NW; u++) {                         \
        f16x2 pr = rowp[cp + SOFF + u];                                        \
        vv[2 * u]     = (float)pr[0];                                          \
        vv[2 * u + 1] = (float)pr[1];                                          \
      }                                                                        \
      _Pragma("unroll") for (int rr = 0; rr < 16; rr++) {                      \
        int dy = iy - rr;                                                      \
        if (dy >= 0 && dy < KS) {                                              \
          _Pragma("unroll") for (int dx = 0; dx < KS; dx++) {                  \
            int m = (8 - P) + dx - 2 * SOFF;                                   \
            a0[rr] += vv[m]     * w[dy * KS + dx];                             \
            a1[rr] += vv[m + 1] * w[dy * KS + dx];                             \
          }                                                                    \
        }                                                                      \
      }                                                                        \
    }                                                                          \
    f16* op = yh2 + (size_t)(b * 48 + BR * 16 + ko) * HW * 8;                  \
    _Pragma("unroll") for (int rr = 0; rr < 16; rr++) {                        \
      size_t pa = ((size_t)(r0 + rr) * W + cglob) * 8 + ch;                    \
      op[pa]     = (f16)a0[rr];                                                \
      op[pa + 8] = (f16)a1[rr];                                                \
    }                                                                          \
  }

  CONV_BRANCH(3, 0, WS_WE3, 3, 3)
  CONV_BRANCH(5, 1, WS_WE5, 3, 3)
  CONV_BRANCH(7, 2, WS_WE7, 5, 2)
#undef CONV_BRANCH
}

// ---------------------------------------------------------------------------
// Kernel Fm: merged final pointwise, f16 MFMA, K=384. Barrier-free, LDS-free,
// 64-px blocks. Epilogue: + pw_b + residual x, NONTEMPORAL out stores (out is
// never re-read; avoid evicting x/yh2 from L3 mid-kernel).
// ---------------------------------------------------------------------------
__global__ __launch_bounds__(256) void kFm(const float* __restrict__ x,
                                           const float* __restrict__ pw_b,
                                           const float* __restrict__ ws,
                                           float* __restrict__ out) {
  const f16* wt2g = (const f16*)(ws + WS_WT2G);
  const f16* yh2  = (const f16*)(ws + WS_BIG);
  int b  = blockIdx.z;
  int p0 = blockIdx.x * 64;

  int t = threadIdx.x, l = t & 63, w = t >> 6;
  int q = l >> 4, n = l & 15;

  f32x4 acc[4][4];
#pragma unroll
  for (int i = 0; i < 4; i++)
#pragma unroll
    for (int j = 0; j < 4; j++)
#pragma unroll
      for (int r = 0; r < 4; r++) acc[i][j][r] = 0.f;

  const f16* bbase = yh2 + (size_t)(b * 48 + q) * (HW * 8) + (size_t)(p0 + n) * 8;
  const f16* abase = wt2g + (size_t)(w * 4) * 512 + (size_t)l * 8;

#pragma unroll 2
  for (int ks = 0; ks < 12; ks++) {
    f16x8 afr[4], bfr[4];
#pragma unroll
    for (int mt = 0; mt < 4; mt++)
      afr[mt] = *(const f16x8*)(abase + (size_t)(ks * 16 + mt) * 512);
#pragma unroll
    for (int nt = 0; nt < 4; nt++)
      bfr[nt] = *(const f16x8*)(bbase + (size_t)ks * (4 * HW * 8) + nt * 128);
#pragma unroll
    for (int mt = 0; mt < 4; mt++)
#pragma unroll
      for (int nt = 0; nt < 4; nt++)
        acc[mt][nt] = __builtin_amdgcn_mfma_f32_16x16x32_f16(afr[mt], bfr[nt],
                                                             acc[mt][nt], 0, 0, 0);
  }

#pragma unroll
  for (int mt = 0; mt < 4; mt++) {
    int obase = w * 64 + mt * 16 + q * 4;
    float bias[4];
#pragma unroll
    for (int r = 0; r < 4; r++) bias[r] = pw_b[obase + r];
#pragma unroll
    for (int nt = 0; nt < 4; nt++) {
      int p = p0 + nt * 16 + n;
#pragma unroll
      for (int r = 0; r < 4; r++) {
        size_t idx = ((size_t)b * O + obase + r) * HW + p;
        __builtin_nontemporal_store(acc[mt][nt][r] + bias[r] + x[idx], &out[idx]);
      }
    }
  }
}

// ---------------------------------------------------------------------------
extern "C" void kernel_launch(void* const* d_in, const int* in_sizes, int n_in,
                              void* d_out, int out_size, void* d_ws, size_t ws_size,
                              hipStream_t stream) {
  const float* x     = (const float*)d_in[0];
  const float* pw1_w = (const float*)d_in[1];
  const float* pw1_b = (const float*)d_in[2];
  const float* fc1_w = (const float*)d_in[3];
  const float* fc1_b = (const float*)d_in[4];
  const float* fc2_w = (const float*)d_in[5];
  const float* fc2_b = (const float*)d_in[6];
  const float* off_w = (const float*)d_in[7];
  const float* off_b = (const float*)d_in[8];
  const float* dw3   = (const float*)d_in[9];
  const float* dw5   = (const float*)d_in[10];
  const float* dw7   = (const float*)d_in[11];
  const float* pw_w  = (const float*)d_in[12];
  const float* pw_b  = (const float*)d_in[13];
  float* out = (float*)d_out;
  float* ws  = (float*)d_ws;

  kT<<<384, 256, 0, stream>>>(pw1_w, pw_w, ws);
  kAT<<<dim3(HW / 256, 32, B), 256, 0, stream>>>(x, ws);
  kB<<<B, 256, 0, stream>>>(pw1_w, pw1_b, fc1_w, fc1_b, fc2_w, fc2_b, ws);
  kCm<<<dim3(HW / 64, 1, B), 256, 0, stream>>>(pw1_b, ws);
  kD1<<<1, 256, 0, stream>>>(off_w, off_b, ws);
  kD2<<<84, 256, 0, stream>>>(dw3, dw5, dw7, ws);
  kEm<<<dim3(16, 16, B), 256, 0, stream>>>(ws, ws);
  kFm<<<dim3(HW / 64, 1, B), 256, 0, stream>>>(x, pw_b, ws, out);
}

// Round 6
// 570.420 us; speedup vs baseline: 1.1465x; 1.0061x over previous
//
#include <hip/hip_runtime.h>
#include <math.h>

// Problem constants
constexpr int B  = 8;
constexpr int C  = 256;   // Cin
constexpr int M  = 256;
constexpr int O  = 256;
constexpr int H  = 128;
constexpr int W  = 128;
constexpr int HW = H * W; // 16384
constexpr int K  = 128;   // top-k / kept channels

using f16   = _Float16;
using f16x2 = __attribute__((ext_vector_type(2))) _Float16;
using f16x8 = __attribute__((ext_vector_type(8))) _Float16;
using f32x4 = __attribute__((ext_vector_type(4))) float;

// Workspace layout (offsets in float units)
constexpr size_t WS_MEANX = 0;        // 2048
constexpr size_t WS_MASK  = 2048;     // 2048
constexpr size_t WS_G2    = 4096;     // 2048
constexpr size_t WS_OFF   = 6144;     // 48 (pad to 64)
constexpr size_t WS_WE3   = 6208;     // 9216
constexpr size_t WS_WE5   = 15424;    // 25600
constexpr size_t WS_WE7   = 41024;    // 50176
constexpr size_t WS_WT1G  = 91200;    // 65536 f16 (pw1_w fragment-linear)
constexpr size_t WS_WT2G  = 123968;   // 98304 f16 (pw_w[:, :384] fragment-linear)
constexpr size_t WS_SELH  = 173120;   // B*K*HW f16 = 8388608 float slots (33.5 MB)
// BIG region: union of xh (B*C*HW f16, dead after kCm) and yh2 (3*B*K*HW f16)
constexpr size_t WS_BIG   = 8561728;
// end = 33727552 floats = 134.91 MB (same proven footprint as before)

// ---------------------------------------------------------------------------
// Kernel T: fragment-linear f16 weight copies + zero meanx/gap2sum.
// ---------------------------------------------------------------------------
__global__ __launch_bounds__(256) void kT(const float* __restrict__ pw1_w,
                                          const float* __restrict__ pw_w,
                                          float* __restrict__ ws) {
  f16* wt1g = (f16*)(ws + WS_WT1G);
  f16* wt2g = (f16*)(ws + WS_WT2G);
  int t = blockIdx.x * 256 + threadIdx.x;
  if (t < 65536) {
    int ks = t >> 13, fr = (t >> 9) & 15, l = (t >> 3) & 63, j = t & 7;
    int o = fr * 16 + (l & 15);
    int c = ks * 32 + ((l >> 4) << 3) + j;
    wt1g[t] = (f16)pw1_w[o * C + c];
  }
  if (t < 98304) {
    int ks = t >> 13, fr = (t >> 9) & 15, l = (t >> 3) & 63, j = t & 7;
    int o = fr * 16 + (l & 15);
    int cc = ks * 32 + ((l >> 4) << 3) + j;
    wt2g[t] = (f16)pw_w[(size_t)o * 768 + cc];
  }
  if (t < 2048) {
    ws[WS_MEANX + t] = 0.f;
    ws[WS_G2 + t]    = 0.f;
  }
}

// ---------------------------------------------------------------------------
// Kernel AT: read x once; per-channel means (atomic partials) and xh = f16 x
// in octet-interleaved layout xh[((b*32+ko)*HW + p)*8 + j], k = 8ko+j.
// ---------------------------------------------------------------------------
__global__ __launch_bounds__(256) void kAT(const float* __restrict__ x,
                                           float* __restrict__ ws) {
  float* meanx = ws + WS_MEANX;
  f16* xh      = (f16*)(ws + WS_BIG);
  int b = blockIdx.z, ko = blockIdx.y, p0 = blockIdx.x * 256;
  __shared__ float sx[8][256];
  int t = threadIdx.x;
  int c8 = t >> 5, pg = t & 31;
  const float* xp = x + (size_t)(b * 256 + ko * 8 + c8) * HW + p0 + pg * 8;
  float4 v0 = ((const float4*)xp)[0];
  float4 v1 = ((const float4*)xp)[1];
  *(float4*)&sx[c8][pg * 8]     = v0;
  *(float4*)&sx[c8][pg * 8 + 4] = v1;
  float s = v0.x + v0.y + v0.z + v0.w + v1.x + v1.y + v1.z + v1.w;
#pragma unroll
  for (int off = 16; off > 0; off >>= 1) s += __shfl_xor(s, off, 32);
  if (pg == 0) atomicAdd(&meanx[b * 256 + ko * 8 + c8], s * (1.f / HW));
  __syncthreads();
  f16x8 o;
#pragma unroll
  for (int j = 0; j < 8; j++) o[j] = (f16)sx[j][t];
  *(f16x8*)&xh[((size_t)(b * 32 + ko) * HW + p0 + t) * 8] = o;
}

// ---------------------------------------------------------------------------
// Kernel B: per-batch block; exact fp32 scoring path (unchanged).
// ---------------------------------------------------------------------------
__global__ __launch_bounds__(256) void kB(const float* __restrict__ pw1_w,
                                          const float* __restrict__ pw1_b,
                                          const float* __restrict__ fc1_w,
                                          const float* __restrict__ fc1_b,
                                          const float* __restrict__ fc2_w,
                                          const float* __restrict__ fc2_b,
                                          float* __restrict__ ws) {
  int b = blockIdx.x;
  const float* meanx = ws + WS_MEANX + b * C;
  float* maskg = ws + WS_MASK;
  __shared__ float s_gap[M];
  __shared__ float s_hid[512];
  __shared__ float s_sc[M];
  int t = threadIdx.x;
  int lane = t & 63, wv = t >> 6;

  float4 mx = ((const float4*)meanx)[lane];
  for (int o0 = wv * 64; o0 < wv * 64 + 64; o0 += 4) {
    float s[4];
#pragma unroll
    for (int j = 0; j < 4; j++) {
      float4 w = ((const float4*)(pw1_w + (size_t)(o0 + j) * C))[lane];
      s[j] = mx.x * w.x + mx.y * w.y + mx.z * w.z + mx.w * w.w;
    }
#pragma unroll
    for (int off = 32; off > 0; off >>= 1)
#pragma unroll
      for (int j = 0; j < 4; j++) s[j] += __shfl_xor(s[j], off, 64);
    if (lane == 0) {
#pragma unroll
      for (int j = 0; j < 4; j++) s_gap[o0 + j] = s[j] + pw1_b[o0 + j];
    }
  }
  __syncthreads();

  float4 g4 = ((const float4*)s_gap)[lane];
  for (int j0 = wv * 128; j0 < wv * 128 + 128; j0 += 4) {
    float s[4];
#pragma unroll
    for (int j = 0; j < 4; j++) {
      float4 w = ((const float4*)(fc1_w + (size_t)(j0 + j) * M))[lane];
      s[j] = g4.x * w.x + g4.y * w.y + g4.z * w.z + g4.w * w.w;
    }
#pragma unroll
    for (int off = 32; off > 0; off >>= 1)
#pragma unroll
      for (int j = 0; j < 4; j++) s[j] += __shfl_xor(s[j], off, 64);
    if (lane == 0) {
#pragma unroll
      for (int j = 0; j < 4; j++) {
        float v = s[j] + fc1_b[j0 + j];
        s_hid[j0 + j] = v > 0.f ? v : 0.f;
      }
    }
  }
  __syncthreads();

  float4 h0 = ((const float4*)s_hid)[lane];
  float4 h1 = ((const float4*)s_hid)[lane + 64];
  for (int o0 = wv * 64; o0 < wv * 64 + 64; o0 += 4) {
    float s[4];
#pragma unroll
    for (int j = 0; j < 4; j++) {
      const float4* wr = (const float4*)(fc2_w + (size_t)(o0 + j) * 512);
      float4 w0 = wr[lane];
      float4 w1 = wr[lane + 64];
      s[j] = h0.x * w0.x + h0.y * w0.y + h0.z * w0.z + h0.w * w0.w +
             h1.x * w1.x + h1.y * w1.y + h1.z * w1.z + h1.w * w1.w;
    }
#pragma unroll
    for (int off = 32; off > 0; off >>= 1)
#pragma unroll
      for (int j = 0; j < 4; j++) s[j] += __shfl_xor(s[j], off, 64);
    if (lane == 0) {
#pragma unroll
      for (int j = 0; j < 4; j++) {
        float v = s[j] + fc2_b[o0 + j];
        s_sc[o0 + j] = 1.f / (1.f + expf(-v));
      }
    }
  }
  __syncthreads();

  {
    int j = t;
    float sj = s_sc[j];
    int cnt = 0;
    for (int m = 0; m < M; m++) {
      float sm = s_sc[m];
      cnt += (sm > sj) || (sm == sj && m < j);
    }
    maskg[b * M + j] = (cnt < K) ? 1.f : 0.f;
  }
}

// ---------------------------------------------------------------------------
// Kernel Cm: h = relu(pw1(x)) via f16 MFMA. Barrier-free, LDS-free.
// 64-px blocks. Bias folded into accumulator init (MFMA C-in chaining).
// ---------------------------------------------------------------------------
__global__ __launch_bounds__(256) void kCm(const float* __restrict__ pw1_b,
                                           float* __restrict__ ws) {
  const f16* wt1g = (const f16*)(ws + WS_WT1G);
  const f16* xh   = (const f16*)(ws + WS_BIG);
  float* gap2sum  = ws + WS_G2;
  f16* selh       = (f16*)(ws + WS_SELH);
  int b  = blockIdx.z;
  int p0 = blockIdx.x * 64;

  int t = threadIdx.x, l = t & 63, w = t >> 6;
  int q = l >> 4, n = l & 15;

  f32x4 acc[4][4];
#pragma unroll
  for (int mt = 0; mt < 4; mt++) {
    int obase = w * 64 + mt * 16 + q * 4;
#pragma unroll
    for (int nt = 0; nt < 4; nt++)
#pragma unroll
      for (int r = 0; r < 4; r++) acc[mt][nt][r] = pw1_b[obase + r];
  }

  const f16* bbase = xh + (size_t)(b * 32 + q) * (HW * 8) + (size_t)(p0 + n) * 8;
  const f16* abase = wt1g + (size_t)(w * 4) * 512 + (size_t)l * 8;

#pragma unroll 2
  for (int ks = 0; ks < 8; ks++) {
    f16x8 afr[4], bfr[4];
#pragma unroll
    for (int mt = 0; mt < 4; mt++)
      afr[mt] = *(const f16x8*)(abase + (size_t)(ks * 16 + mt) * 512);
#pragma unroll
    for (int nt = 0; nt < 4; nt++)
      bfr[nt] = *(const f16x8*)(bbase + (size_t)ks * (4 * HW * 8) + nt * 128);
#pragma unroll
    for (int mt = 0; mt < 4; mt++)
#pragma unroll
      for (int nt = 0; nt < 4; nt++)
        acc[mt][nt] = __builtin_amdgcn_mfma_f32_16x16x32_f16(afr[mt], bfr[nt],
                                                             acc[mt][nt], 0, 0, 0);
  }

  // Epilogue: relu; sel f16 store (o<128); gap2sum partial sums
#pragma unroll
  for (int mt = 0; mt < 4; mt++) {
    float rsum[4] = {0.f, 0.f, 0.f, 0.f};
    int obase = w * 64 + mt * 16 + q * 4;
#pragma unroll
    for (int nt = 0; nt < 4; nt++) {
      int p = p0 + nt * 16 + n;
#pragma unroll
      for (int r = 0; r < 4; r++) {
        float h = acc[mt][nt][r];
        h = h > 0.f ? h : 0.f;
        rsum[r] += h;
        int o = obase + r;
        if (o < K) selh[((size_t)(b * K + o)) * HW + p] = (f16)h;
      }
    }
#pragma unroll
    for (int off = 1; off < 16; off <<= 1)
#pragma unroll
      for (int r = 0; r < 4; r++) rsum[r] += __shfl_xor(rsum[r], off, 64);
    if (n == 0) {
#pragma unroll
      for (int r = 0; r < 4; r++)
        atomicAdd(&gap2sum[b * M + obase + r], rsum[r]);
    }
  }
}

// ---------------------------------------------------------------------------
// Kernel D1 (1 block): offsets from gap2; emit per-(b,branch) scale/shift.
// ---------------------------------------------------------------------------
__global__ __launch_bounds__(256) void kD1(const float* __restrict__ off_w,
                                           const float* __restrict__ off_b,
                                           float* __restrict__ ws) {
  const float* gap2sum = ws + WS_G2;
  float* offv = ws + WS_OFF;  // [0..23]=scale(b*3+i), [24..47]=shift
  __shared__ float s_off[48];
  int t = threadIdx.x;
  int lane = t & 63, wv = t >> 6;
  for (int id = wv; id < 48; id += 4) {
    int b = id / 6, j = id % 6;
    float4 g = ((const float4*)(gap2sum + b * M))[lane];
    float4 w = ((const float4*)(off_w + (size_t)j * M))[lane];
    float s = (g.x * w.x + g.y * w.y + g.z * w.z + g.w * w.w) * (1.f / HW);
#pragma unroll
    for (int off = 32; off > 0; off >>= 1) s += __shfl_xor(s, off, 64);
    if (lane == 0) s_off[id] = tanhf(s + off_b[j]);
  }
  __syncthreads();
  if (t < 24) {
    int b = t / 3, i = t % 3;
    offv[t]      = 1.f + 1.f / (1.f + expf(-s_off[b * 6 + 2 * i]));
    offv[24 + t] = tanhf(s_off[b * 6 + 2 * i + 1]);
  }
}

// ---------------------------------------------------------------------------
// Kernel D2: effective depthwise weights, with top-k mask folded in.
// ---------------------------------------------------------------------------
__global__ __launch_bounds__(256) void kD2(const float* __restrict__ dw3,
                                           const float* __restrict__ dw5,
                                           const float* __restrict__ dw7,
                                           float* __restrict__ ws) {
  const float* offv  = ws + WS_OFF;
  const float* maskg = ws + WS_MASK;
  float* wE3 = ws + WS_WE3;
  float* wE5 = ws + WS_WE5;
  float* wE7 = ws + WS_WE7;
  int tid = blockIdx.x * 256 + threadIdx.x;
  int stride = gridDim.x * 256;
  for (int i = tid; i < B * K * 9; i += stride) {
    int b = i / (K * 9), rem = i % (K * 9), c = rem / 9;
    wE3[i] = (dw3[rem] * offv[b * 3 + 0] + offv[24 + b * 3 + 0]) * maskg[b * M + c];
  }
  for (int i = tid; i < B * K * 25; i += stride) {
    int b = i / (K * 25), rem = i % (K * 25), c = rem / 25;
    wE5[i] = (dw5[rem] * offv[b * 3 + 1] + offv[24 + b * 3 + 1]) * maskg[b * M + c];
  }
  for (int i = tid; i < B * K * 49; i += stride) {
    int b = i / (K * 49), rem = i % (K * 49), c = rem / 49;
    wE7[i] = (dw7[rem] * offv[b * 3 + 2] + offv[24 + b * 3 + 2]) * maskg[b * M + c];
  }
}

// ---------------------------------------------------------------------------
// Kernel Em: merged depthwise conv. f16 halo in LDS; compute = f16x2 LDS
// reads -> cvt -> fp32 fma. Vectorized fill: halo row origin c0-8 is
// 8-aligned -> pure f16x8 chunks. Plane stride 1768 f16 (884 dw % 32 = 20).
// Block: 256 thr = 8 ch x 32 col-pairs; 16 rows x 64 cols x 8 ch per block.
// ---------------------------------------------------------------------------
__global__ __launch_bounds__(256) void kEm(const float* __restrict__ ws_ro,
                                           float* __restrict__ ws) {
  constexpr int SP = 1768;  // f16 per channel plane (22 rows x 80 + pad)
  __shared__ f16 sm[8 * SP];  // 28288 B
  const f16* selh = (const f16*)(ws_ro + WS_SELH);
  f16* yh2        = (f16*)(ws + WS_BIG);
  int bx = blockIdx.x;
  int slab = bx >> 1, chalf = bx & 1;
  int ko = blockIdx.y, b = blockIdx.z;
  int r0 = slab * 16, c0 = chalf * 64;

  // Fill: per (ch, row rr of 22, chunk of 10): one f16x8 from global or zeros.
  // LDS row col L corresponds to global col c0 - 8 + L.
  for (int i = threadIdx.x; i < 8 * 220; i += 256) {
    int chn = i / 220, rem = i - chn * 220;
    int rr = rem / 10, chunk = rem - rr * 10;
    int gy = r0 - 3 + rr, g0 = c0 - 8 + chunk * 8;
    f16x8 v = {};
    if (gy >= 0 && gy < H && g0 >= 0 && g0 < W)
      v = *(const f16x8*)&selh[(size_t)(b * 128 + ko * 8 + chn) * HW + gy * W + g0];
    *(f16x8*)&sm[chn * SP + rr * 80 + chunk * 8] = v;
  }
  __syncthreads();

  int t = threadIdx.x;
  int ch = t & 7, cp = t >> 3;  // channel 0..7, col-pair 0..31
  int cglob = c0 + cp * 2;

  // Tap f16-index within the vv window: even col: (8-P)+dx-2*SOFF,
  // odd col: (9-P)+dx-2*SOFF. (KS,NW,SOFF) = (3,3,3),(5,3,3),(7,5,2).
#define CONV_BRANCH(KS, BR, WSOFF, NW, SOFF)                                   \
  {                                                                            \
    constexpr int P = (KS - 1) / 2;                                            \
    const float* wp = ws_ro + WSOFF + (size_t)(b * 128 + ko * 8 + ch) * (KS*KS); \
    float w[KS * KS];                                                          \
    _Pragma("unroll") for (int i = 0; i < KS * KS; i++) w[i] = wp[i];          \
    float a0[16], a1[16];                                                      \
    _Pragma("unroll") for (int r = 0; r < 16; r++) { a0[r] = 0.f; a1[r] = 0.f; } \
    _Pragma("unroll") for (int iy = 0; iy < 16 + 2 * P; iy++) {                \
      int hr = iy + (3 - P);                                                   \
      const f16x2* rowp = (const f16x2*)(sm + ch * SP + hr * 80);              \
      float vv[2 * NW];                                                        \
      _Pragma("unroll") for (int u = 0; u < NW; u++) {                         \
        f16x2 pr = rowp[cp + SOFF + u];                                        \
        vv[2 * u]     = (float)pr[0];                                          \
        vv[2 * u + 1] = (float)pr[1];                                          \
      }                                                                        \
      _Pragma("unroll") for (int rr = 0; rr < 16; rr++) {                      \
        int dy = iy - rr;                                                      \
        if (dy >= 0 && dy < KS) {                                              \
          _Pragma("unroll") for (int dx = 0; dx < KS; dx++) {                  \
            int m = (8 - P) + dx - 2 * SOFF;                                   \
            a0[rr] += vv[m]     * w[dy * KS + dx];                             \
            a1[rr] += vv[m + 1] * w[dy * KS + dx];                             \
          }                                                                    \
        }                                                                      \
      }                                                                        \
    }                                                                          \
    f16* op = yh2 + (size_t)(b * 48 + BR * 16 + ko) * HW * 8;                  \
    _Pragma("unroll") for (int rr = 0; rr < 16; rr++) {                        \
      size_t pa = ((size_t)(r0 + rr) * W + cglob) * 8 + ch;                    \
      op[pa]     = (f16)a0[rr];                                                \
      op[pa + 8] = (f16)a1[rr];                                                \
    }                                                                          \
  }

  CONV_BRANCH(3, 0, WS_WE3, 3, 3)
  CONV_BRANCH(5, 1, WS_WE5, 3, 3)
  CONV_BRANCH(7, 2, WS_WE7, 5, 2)
#undef CONV_BRANCH
}

// ---------------------------------------------------------------------------
// Kernel Fm: merged final pointwise, f16 MFMA, K=384. Barrier-free, LDS-free,
// 64-px blocks. Residual + bias folded into accumulator INIT (MFMA C-in):
// the 64 x loads issue at block start and complete under the MFMA loop
// (oldest in vmcnt queue), spreading HBM reads across the kernel instead of
// bursting in the epilogue. Epilogue = pure stores (plain; nt inflated
// WRITE_SIZE 137->162 MB with no read-side gain).
// ---------------------------------------------------------------------------
__global__ __launch_bounds__(256) void kFm(const float* __restrict__ x,
                                           const float* __restrict__ pw_b,
                                           const float* __restrict__ ws,
                                           float* __restrict__ out) {
  const f16* wt2g = (const f16*)(ws + WS_WT2G);
  const f16* yh2  = (const f16*)(ws + WS_BIG);
  int b  = blockIdx.z;
  int p0 = blockIdx.x * 64;

  int t = threadIdx.x, l = t & 63, w = t >> 6;
  int q = l >> 4, n = l & 15;

  f32x4 acc[4][4];
#pragma unroll
  for (int mt = 0; mt < 4; mt++) {
    int obase = w * 64 + mt * 16 + q * 4;
    float b4[4];
#pragma unroll
    for (int r = 0; r < 4; r++) b4[r] = pw_b[obase + r];
#pragma unroll
    for (int nt = 0; nt < 4; nt++) {
      int p = p0 + nt * 16 + n;
#pragma unroll
      for (int r = 0; r < 4; r++) {
        size_t idx = ((size_t)b * O + obase + r) * HW + p;
        acc[mt][nt][r] = b4[r] + x[idx];
      }
    }
  }

  const f16* bbase = yh2 + (size_t)(b * 48 + q) * (HW * 8) + (size_t)(p0 + n) * 8;
  const f16* abase = wt2g + (size_t)(w * 4) * 512 + (size_t)l * 8;

#pragma unroll 2
  for (int ks = 0; ks < 12; ks++) {
    f16x8 afr[4], bfr[4];
#pragma unroll
    for (int mt = 0; mt < 4; mt++)
      afr[mt] = *(const f16x8*)(abase + (size_t)(ks * 16 + mt) * 512);
#pragma unroll
    for (int nt = 0; nt < 4; nt++)
      bfr[nt] = *(const f16x8*)(bbase + (size_t)ks * (4 * HW * 8) + nt * 128);
#pragma unroll
    for (int mt = 0; mt < 4; mt++)
#pragma unroll
      for (int nt = 0; nt < 4; nt++)
        acc[mt][nt] = __builtin_amdgcn_mfma_f32_16x16x32_f16(afr[mt], bfr[nt],
                                                             acc[mt][nt], 0, 0, 0);
  }

#pragma unroll
  for (int mt = 0; mt < 4; mt++) {
    int obase = w * 64 + mt * 16 + q * 4;
#pragma unroll
    for (int nt = 0; nt < 4; nt++) {
      int p = p0 + nt * 16 + n;
#pragma unroll
      for (int r = 0; r < 4; r++) {
        size_t idx = ((size_t)b * O + obase + r) * HW + p;
        out[idx] = acc[mt][nt][r];
      }
    }
  }
}

// ---------------------------------------------------------------------------
extern "C" void kernel_launch(void* const* d_in, const int* in_sizes, int n_in,
                              void* d_out, int out_size, void* d_ws, size_t ws_size,
                              hipStream_t stream) {
  const float* x     = (const float*)d_in[0];
  const float* pw1_w = (const float*)d_in[1];
  const float* pw1_b = (const float*)d_in[2];
  const float* fc1_w = (const float*)d_in[3];
  const float* fc1_b = (const float*)d_in[4];
  const float* fc2_w = (const float*)d_in[5];
  const float* fc2_b = (const float*)d_in[6];
  const float* off_w = (const float*)d_in[7];
  const float* off_b = (const float*)d_in[8];
  const float* dw3   = (const float*)d_in[9];
  const float* dw5   = (const float*)d_in[10];
  const float* dw7   = (const float*)d_in[11];
  const float* pw_w  = (const float*)d_in[12];
  const float* pw_b  = (const float*)d_in[13];
  float* out = (float*)d_out;
  float* ws  = (float*)d_ws;

  kT<<<384, 256, 0, stream>>>(pw1_w, pw_w, ws);
  kAT<<<dim3(HW / 256, 32, B), 256, 0, stream>>>(x, ws);
  kB<<<B, 256, 0, stream>>>(pw1_w, pw1_b, fc1_w, fc1_b, fc2_w, fc2_b, ws);
  kCm<<<dim3(HW / 64, 1, B), 256, 0, stream>>>(pw1_b, ws);
  kD1<<<1, 256, 0, stream>>>(off_w, off_b, ws);
  kD2<<<84, 256, 0, stream>>>(dw3, dw5, dw7, ws);
  kEm<<<dim3(16, 16, B), 256, 0, stream>>>(ws, ws);
  kFm<<<dim3(HW / 64, 1, B), 256, 0, stream>>>(x, pw_b, ws, out);
}

// Round 7
// 566.060 us; speedup vs baseline: 1.1554x; 1.0077x over previous
//
#include <hip/hip_runtime.h>
#include <math.h>

// Problem constants
constexpr int B  = 8;
constexpr int C  = 256;   // Cin
constexpr int M  = 256;
constexpr int O  = 256;
constexpr int H  = 128;
constexpr int W  = 128;
constexpr int HW = H * W; // 16384
constexpr int K  = 128;   // top-k / kept channels

using f16   = _Float16;
using f16x2 = __attribute__((ext_vector_type(2))) _Float16;
using f16x8 = __attribute__((ext_vector_type(8))) _Float16;
using f32x4 = __attribute__((ext_vector_type(4))) float;

// Workspace layout (offsets in float units)
constexpr size_t WS_MEANX = 0;        // 2048
constexpr size_t WS_MASK  = 2048;     // 2048
constexpr size_t WS_G2    = 4096;     // 2048
constexpr size_t WS_OFF   = 6144;     // 48 (pad to 64)
constexpr size_t WS_WE3   = 6208;     // 9216
constexpr size_t WS_WE5   = 15424;    // 25600
constexpr size_t WS_WE7   = 41024;    // 50176
constexpr size_t WS_WT1G  = 91200;    // 65536 f16 (pw1_w fragment-linear)
constexpr size_t WS_WT2G  = 123968;   // 98304 f16 (pw_w[:, :384] fragment-linear)
constexpr size_t WS_SELH  = 173120;   // B*K*HW f16 = 8388608 float slots (33.5 MB)
// BIG region: union of xh (B*C*HW f16, dead after kCm) and yh2 (3*B*K*HW f16)
constexpr size_t WS_BIG   = 8561728;
// end = 33727552 floats = 134.91 MB (same proven footprint as before)

// ---------------------------------------------------------------------------
// Kernel T: fragment-linear f16 weight copies + zero meanx/gap2sum.
// ---------------------------------------------------------------------------
__global__ __launch_bounds__(256) void kT(const float* __restrict__ pw1_w,
                                          const float* __restrict__ pw_w,
                                          float* __restrict__ ws) {
  f16* wt1g = (f16*)(ws + WS_WT1G);
  f16* wt2g = (f16*)(ws + WS_WT2G);
  int t = blockIdx.x * 256 + threadIdx.x;
  if (t < 65536) {
    int ks = t >> 13, fr = (t >> 9) & 15, l = (t >> 3) & 63, j = t & 7;
    int o = fr * 16 + (l & 15);
    int c = ks * 32 + ((l >> 4) << 3) + j;
    wt1g[t] = (f16)pw1_w[o * C + c];
  }
  if (t < 98304) {
    int ks = t >> 13, fr = (t >> 9) & 15, l = (t >> 3) & 63, j = t & 7;
    int o = fr * 16 + (l & 15);
    int cc = ks * 32 + ((l >> 4) << 3) + j;
    wt2g[t] = (f16)pw_w[(size_t)o * 768 + cc];
  }
  if (t < 2048) {
    ws[WS_MEANX + t] = 0.f;
    ws[WS_G2 + t]    = 0.f;
  }
}

// ---------------------------------------------------------------------------
// Kernel AT: read x once; per-channel means (atomic partials) and xh = f16 x
// in octet-interleaved layout xh[((b*32+ko)*HW + p)*8 + j], k = 8ko+j.
// ---------------------------------------------------------------------------
__global__ __launch_bounds__(256) void kAT(const float* __restrict__ x,
                                           float* __restrict__ ws) {
  float* meanx = ws + WS_MEANX;
  f16* xh      = (f16*)(ws + WS_BIG);
  int b = blockIdx.z, ko = blockIdx.y, p0 = blockIdx.x * 256;
  __shared__ float sx[8][256];
  int t = threadIdx.x;
  int c8 = t >> 5, pg = t & 31;
  const float* xp = x + (size_t)(b * 256 + ko * 8 + c8) * HW + p0 + pg * 8;
  float4 v0 = ((const float4*)xp)[0];
  float4 v1 = ((const float4*)xp)[1];
  *(float4*)&sx[c8][pg * 8]     = v0;
  *(float4*)&sx[c8][pg * 8 + 4] = v1;
  float s = v0.x + v0.y + v0.z + v0.w + v1.x + v1.y + v1.z + v1.w;
#pragma unroll
  for (int off = 16; off > 0; off >>= 1) s += __shfl_xor(s, off, 32);
  if (pg == 0) atomicAdd(&meanx[b * 256 + ko * 8 + c8], s * (1.f / HW));
  __syncthreads();
  f16x8 o;
#pragma unroll
  for (int j = 0; j < 8; j++) o[j] = (f16)sx[j][t];
  *(f16x8*)&xh[((size_t)(b * 32 + ko) * HW + p0 + t) * 8] = o;
}

// ---------------------------------------------------------------------------
// Kernel B: per-batch block; exact fp32 scoring path (unchanged).
// ---------------------------------------------------------------------------
__global__ __launch_bounds__(256) void kB(const float* __restrict__ pw1_w,
                                          const float* __restrict__ pw1_b,
                                          const float* __restrict__ fc1_w,
                                          const float* __restrict__ fc1_b,
                                          const float* __restrict__ fc2_w,
                                          const float* __restrict__ fc2_b,
                                          float* __restrict__ ws) {
  int b = blockIdx.x;
  const float* meanx = ws + WS_MEANX + b * C;
  float* maskg = ws + WS_MASK;
  __shared__ float s_gap[M];
  __shared__ float s_hid[512];
  __shared__ float s_sc[M];
  int t = threadIdx.x;
  int lane = t & 63, wv = t >> 6;

  float4 mx = ((const float4*)meanx)[lane];
  for (int o0 = wv * 64; o0 < wv * 64 + 64; o0 += 4) {
    float s[4];
#pragma unroll
    for (int j = 0; j < 4; j++) {
      float4 w = ((const float4*)(pw1_w + (size_t)(o0 + j) * C))[lane];
      s[j] = mx.x * w.x + mx.y * w.y + mx.z * w.z + mx.w * w.w;
    }
#pragma unroll
    for (int off = 32; off > 0; off >>= 1)
#pragma unroll
      for (int j = 0; j < 4; j++) s[j] += __shfl_xor(s[j], off, 64);
    if (lane == 0) {
#pragma unroll
      for (int j = 0; j < 4; j++) s_gap[o0 + j] = s[j] + pw1_b[o0 + j];
    }
  }
  __syncthreads();

  float4 g4 = ((const float4*)s_gap)[lane];
  for (int j0 = wv * 128; j0 < wv * 128 + 128; j0 += 4) {
    float s[4];
#pragma unroll
    for (int j = 0; j < 4; j++) {
      float4 w = ((const float4*)(fc1_w + (size_t)(j0 + j) * M))[lane];
      s[j] = g4.x * w.x + g4.y * w.y + g4.z * w.z + g4.w * w.w;
    }
#pragma unroll
    for (int off = 32; off > 0; off >>= 1)
#pragma unroll
      for (int j = 0; j < 4; j++) s[j] += __shfl_xor(s[j], off, 64);
    if (lane == 0) {
#pragma unroll
      for (int j = 0; j < 4; j++) {
        float v = s[j] + fc1_b[j0 + j];
        s_hid[j0 + j] = v > 0.f ? v : 0.f;
      }
    }
  }
  __syncthreads();

  float4 h0 = ((const float4*)s_hid)[lane];
  float4 h1 = ((const float4*)s_hid)[lane + 64];
  for (int o0 = wv * 64; o0 < wv * 64 + 64; o0 += 4) {
    float s[4];
#pragma unroll
    for (int j = 0; j < 4; j++) {
      const float4* wr = (const float4*)(fc2_w + (size_t)(o0 + j) * 512);
      float4 w0 = wr[lane];
      float4 w1 = wr[lane + 64];
      s[j] = h0.x * w0.x + h0.y * w0.y + h0.z * w0.z + h0.w * w0.w +
             h1.x * w1.x + h1.y * w1.y + h1.z * w1.z + h1.w * w1.w;
    }
#pragma unroll
    for (int off = 32; off > 0; off >>= 1)
#pragma unroll
      for (int j = 0; j < 4; j++) s[j] += __shfl_xor(s[j], off, 64);
    if (lane == 0) {
#pragma unroll
      for (int j = 0; j < 4; j++) {
        float v = s[j] + fc2_b[o0 + j];
        s_sc[o0 + j] = 1.f / (1.f + expf(-v));
      }
    }
  }
  __syncthreads();

  {
    int j = t;
    float sj = s_sc[j];
    int cnt = 0;
    for (int m = 0; m < M; m++) {
      float sm = s_sc[m];
      cnt += (sm > sj) || (sm == sj && m < j);
    }
    maskg[b * M + j] = (cnt < K) ? 1.f : 0.f;
  }
}

// ---------------------------------------------------------------------------
// Kernel Cm: h = relu(pw1(x)) via f16 MFMA. Barrier-free, LDS-free, 64-px
// blocks. Explicit depth-1 software pipeline: A/B fragments double-buffered
// in registers, k+1 loads issued before consuming k (static buffer names,
// fully unrolled loop). Bias folded into accumulator init.
// ---------------------------------------------------------------------------
__global__ __launch_bounds__(256) void kCm(const float* __restrict__ pw1_b,
                                           float* __restrict__ ws) {
  const f16* wt1g = (const f16*)(ws + WS_WT1G);
  const f16* xh   = (const f16*)(ws + WS_BIG);
  float* gap2sum  = ws + WS_G2;
  f16* selh       = (f16*)(ws + WS_SELH);
  int b  = blockIdx.z;
  int p0 = blockIdx.x * 64;

  int t = threadIdx.x, l = t & 63, w = t >> 6;
  int q = l >> 4, n = l & 15;

  const f16* bbase = xh + (size_t)(b * 32 + q) * (HW * 8) + (size_t)(p0 + n) * 8;
  const f16* abase = wt1g + (size_t)(w * 4) * 512 + (size_t)l * 8;

#define LDA1(dst, ks)                                                          \
  _Pragma("unroll") for (int mt = 0; mt < 4; mt++)                             \
      dst[mt] = *(const f16x8*)(abase + (size_t)((ks) * 16 + mt) * 512);
#define LDB1(dst, ks)                                                          \
  _Pragma("unroll") for (int nt = 0; nt < 4; nt++)                             \
      dst[nt] = *(const f16x8*)(bbase + (size_t)(ks) * (4 * HW * 8) + nt * 128);
#define STEP1(af, bf)                                                          \
  _Pragma("unroll") for (int mt = 0; mt < 4; mt++)                             \
      _Pragma("unroll") for (int nt = 0; nt < 4; nt++)                         \
          acc[mt][nt] = __builtin_amdgcn_mfma_f32_16x16x32_f16(                \
              af[mt], bf[nt], acc[mt][nt], 0, 0, 0);

  f16x8 aA[4], bA[4], aB[4], bB[4];
  LDB1(bA, 0)
  LDA1(aA, 0)

  f32x4 acc[4][4];
#pragma unroll
  for (int mt = 0; mt < 4; mt++) {
    int obase = w * 64 + mt * 16 + q * 4;
#pragma unroll
    for (int nt = 0; nt < 4; nt++)
#pragma unroll
      for (int r = 0; r < 4; r++) acc[mt][nt][r] = pw1_b[obase + r];
  }

#pragma unroll
  for (int ks = 0; ks < 8; ks += 2) {
    if (ks + 1 < 8) { LDB1(bB, ks + 1) LDA1(aB, ks + 1) }
    STEP1(aA, bA)
    if (ks + 2 < 8) { LDB1(bA, ks + 2) LDA1(aA, ks + 2) }
    if (ks + 1 < 8) STEP1(aB, bB)
  }
#undef LDA1
#undef LDB1
#undef STEP1

  // Epilogue: relu; sel f16 store (o<128); gap2sum partial sums
#pragma unroll
  for (int mt = 0; mt < 4; mt++) {
    float rsum[4] = {0.f, 0.f, 0.f, 0.f};
    int obase = w * 64 + mt * 16 + q * 4;
#pragma unroll
    for (int nt = 0; nt < 4; nt++) {
      int p = p0 + nt * 16 + n;
#pragma unroll
      for (int r = 0; r < 4; r++) {
        float h = acc[mt][nt][r];
        h = h > 0.f ? h : 0.f;
        rsum[r] += h;
        int o = obase + r;
        if (o < K) selh[((size_t)(b * K + o)) * HW + p] = (f16)h;
      }
    }
#pragma unroll
    for (int off = 1; off < 16; off <<= 1)
#pragma unroll
      for (int r = 0; r < 4; r++) rsum[r] += __shfl_xor(rsum[r], off, 64);
    if (n == 0) {
#pragma unroll
      for (int r = 0; r < 4; r++)
        atomicAdd(&gap2sum[b * M + obase + r], rsum[r]);
    }
  }
}

// ---------------------------------------------------------------------------
// Kernel D1 (1 block): offsets from gap2; emit per-(b,branch) scale/shift.
// ---------------------------------------------------------------------------
__global__ __launch_bounds__(256) void kD1(const float* __restrict__ off_w,
                                           const float* __restrict__ off_b,
                                           float* __restrict__ ws) {
  const float* gap2sum = ws + WS_G2;
  float* offv = ws + WS_OFF;  // [0..23]=scale(b*3+i), [24..47]=shift
  __shared__ float s_off[48];
  int t = threadIdx.x;
  int lane = t & 63, wv = t >> 6;
  for (int id = wv; id < 48; id += 4) {
    int b = id / 6, j = id % 6;
    float4 g = ((const float4*)(gap2sum + b * M))[lane];
    float4 w = ((const float4*)(off_w + (size_t)j * M))[lane];
    float s = (g.x * w.x + g.y * w.y + g.z * w.z + g.w * w.w) * (1.f / HW);
#pragma unroll
    for (int off = 32; off > 0; off >>= 1) s += __shfl_xor(s, off, 64);
    if (lane == 0) s_off[id] = tanhf(s + off_b[j]);
  }
  __syncthreads();
  if (t < 24) {
    int b = t / 3, i = t % 3;
    offv[t]      = 1.f + 1.f / (1.f + expf(-s_off[b * 6 + 2 * i]));
    offv[24 + t] = tanhf(s_off[b * 6 + 2 * i + 1]);
  }
}

// ---------------------------------------------------------------------------
// Kernel D2: effective depthwise weights, with top-k mask folded in.
// ---------------------------------------------------------------------------
__global__ __launch_bounds__(256) void kD2(const float* __restrict__ dw3,
                                           const float* __restrict__ dw5,
                                           const float* __restrict__ dw7,
                                           float* __restrict__ ws) {
  const float* offv  = ws + WS_OFF;
  const float* maskg = ws + WS_MASK;
  float* wE3 = ws + WS_WE3;
  float* wE5 = ws + WS_WE5;
  float* wE7 = ws + WS_WE7;
  int tid = blockIdx.x * 256 + threadIdx.x;
  int stride = gridDim.x * 256;
  for (int i = tid; i < B * K * 9; i += stride) {
    int b = i / (K * 9), rem = i % (K * 9), c = rem / 9;
    wE3[i] = (dw3[rem] * offv[b * 3 + 0] + offv[24 + b * 3 + 0]) * maskg[b * M + c];
  }
  for (int i = tid; i < B * K * 25; i += stride) {
    int b = i / (K * 25), rem = i % (K * 25), c = rem / 25;
    wE5[i] = (dw5[rem] * offv[b * 3 + 1] + offv[24 + b * 3 + 1]) * maskg[b * M + c];
  }
  for (int i = tid; i < B * K * 49; i += stride) {
    int b = i / (K * 49), rem = i % (K * 49), c = rem / 49;
    wE7[i] = (dw7[rem] * offv[b * 3 + 2] + offv[24 + b * 3 + 2]) * maskg[b * M + c];
  }
}

// ---------------------------------------------------------------------------
// Kernel Em: merged depthwise conv. f16 halo in LDS; compute = f16x2 LDS
// reads -> cvt -> fp32 fma. Vectorized fill: halo row origin c0-8 is
// 8-aligned -> pure f16x8 chunks. Plane stride 1768 f16 (884 dw % 32 = 20).
// Block: 256 thr = 8 ch x 32 col-pairs; 16 rows x 64 cols x 8 ch per block.
// ---------------------------------------------------------------------------
__global__ __launch_bounds__(256) void kEm(const float* __restrict__ ws_ro,
                                           float* __restrict__ ws) {
  constexpr int SP = 1768;  // f16 per channel plane (22 rows x 80 + pad)
  __shared__ f16 sm[8 * SP];  // 28288 B
  const f16* selh = (const f16*)(ws_ro + WS_SELH);
  f16* yh2        = (f16*)(ws + WS_BIG);
  int bx = blockIdx.x;
  int slab = bx >> 1, chalf = bx & 1;
  int ko = blockIdx.y, b = blockIdx.z;
  int r0 = slab * 16, c0 = chalf * 64;

  // Fill: per (ch, row rr of 22, chunk of 10): one f16x8 from global or zeros.
  // LDS row col L corresponds to global col c0 - 8 + L.
  for (int i = threadIdx.x; i < 8 * 220; i += 256) {
    int chn = i / 220, rem = i - chn * 220;
    int rr = rem / 10, chunk = rem - rr * 10;
    int gy = r0 - 3 + rr, g0 = c0 - 8 + chunk * 8;
    f16x8 v = {};
    if (gy >= 0 && gy < H && g0 >= 0 && g0 < W)
      v = *(const f16x8*)&selh[(size_t)(b * 128 + ko * 8 + chn) * HW + gy * W + g0];
    *(f16x8*)&sm[chn * SP + rr * 80 + chunk * 8] = v;
  }
  __syncthreads();

  int t = threadIdx.x;
  int ch = t & 7, cp = t >> 3;  // channel 0..7, col-pair 0..31
  int cglob = c0 + cp * 2;

  // Tap f16-index within the vv window: even col: (8-P)+dx-2*SOFF,
  // odd col: (9-P)+dx-2*SOFF. (KS,NW,SOFF) = (3,3,3),(5,3,3),(7,5,2).
#define CONV_BRANCH(KS, BR, WSOFF, NW, SOFF)                                   \
  {                                                                            \
    constexpr int P = (KS - 1) / 2;                                            \
    const float* wp = ws_ro + WSOFF + (size_t)(b * 128 + ko * 8 + ch) * (KS*KS); \
    float w[KS * KS];                                                          \
    _Pragma("unroll") for (int i = 0; i < KS * KS; i++) w[i] = wp[i];          \
    float a0[16], a1[16];                                                      \
    _Pragma("unroll") for (int r = 0; r < 16; r++) { a0[r] = 0.f; a1[r] = 0.f; } \
    _Pragma("unroll") for (int iy = 0; iy < 16 + 2 * P; iy++) {                \
      int hr = iy + (3 - P);                                                   \
      const f16x2* rowp = (const f16x2*)(sm + ch * SP + hr * 80);              \
      float vv[2 * NW];                                                        \
      _Pragma("unroll") for (int u = 0; u < NW; u++) {                         \
        f16x2 pr = rowp[cp + SOFF + u];                                        \
        vv[2 * u]     = (float)pr[0];                                          \
        vv[2 * u + 1] = (float)pr[1];                                          \
      }                                                                        \
      _Pragma("unroll") for (int rr = 0; rr < 16; rr++) {                      \
        int dy = iy - rr;                                                      \
        if (dy >= 0 && dy < KS) {                                              \
          _Pragma("unroll") for (int dx = 0; dx < KS; dx++) {                  \
            int m = (8 - P) + dx - 2 * SOFF;                                   \
            a0[rr] += vv[m]     * w[dy * KS + dx];                             \
            a1[rr] += vv[m + 1] * w[dy * KS + dx];                             \
          }                                                                    \
        }                                                                      \
      }                                                                        \
    }                                                                          \
    f16* op = yh2 + (size_t)(b * 48 + BR * 16 + ko) * HW * 8;                  \
    _Pragma("unroll") for (int rr = 0; rr < 16; rr++) {                        \
      size_t pa = ((size_t)(r0 + rr) * W + cglob) * 8 + ch;                    \
      op[pa]     = (f16)a0[rr];                                                \
      op[pa + 8] = (f16)a1[rr];                                                \
    }                                                                          \
  }

  CONV_BRANCH(3, 0, WS_WE3, 3, 3)
  CONV_BRANCH(5, 1, WS_WE5, 3, 3)
  CONV_BRANCH(7, 2, WS_WE7, 5, 2)
#undef CONV_BRANCH
}

// ---------------------------------------------------------------------------
// Kernel Fm: merged final pointwise, f16 MFMA, K=384. Barrier-free, LDS-free,
// 64-px blocks. Explicit depth-1 register double-buffer pipeline (A and B
// loads for k+1 issued before consuming k). Residual + bias folded into
// accumulator init; x loads are nontemporal (read-once — keep yh2 L3-hot);
// B(0)/A(0) issued before the x-dependent init so they fly during the x wait.
// ---------------------------------------------------------------------------
__global__ __launch_bounds__(256) void kFm(const float* __restrict__ x,
                                           const float* __restrict__ pw_b,
                                           const float* __restrict__ ws,
                                           float* __restrict__ out) {
  const f16* wt2g = (const f16*)(ws + WS_WT2G);
  const f16* yh2  = (const f16*)(ws + WS_BIG);
  int b  = blockIdx.z;
  int p0 = blockIdx.x * 64;

  int t = threadIdx.x, l = t & 63, w = t >> 6;
  int q = l >> 4, n = l & 15;

  const f16* bbase = yh2 + (size_t)(b * 48 + q) * (HW * 8) + (size_t)(p0 + n) * 8;
  const f16* abase = wt2g + (size_t)(w * 4) * 512 + (size_t)l * 8;

#define LDA2(dst, ks)                                                          \
  _Pragma("unroll") for (int mt = 0; mt < 4; mt++)                             \
      dst[mt] = *(const f16x8*)(abase + (size_t)((ks) * 16 + mt) * 512);
#define LDB2(dst, ks)                                                          \
  _Pragma("unroll") for (int nt = 0; nt < 4; nt++)                             \
      dst[nt] = *(const f16x8*)(bbase + (size_t)(ks) * (4 * HW * 8) + nt * 128);
#define STEP2(af, bf)                                                          \
  _Pragma("unroll") for (int mt = 0; mt < 4; mt++)                             \
      _Pragma("unroll") for (int nt = 0; nt < 4; nt++)                         \
          acc[mt][nt] = __builtin_amdgcn_mfma_f32_16x16x32_f16(                \
              af[mt], bf[nt], acc[mt][nt], 0, 0, 0);

  f16x8 aA[4], bA[4], aB[4], bB[4];
  LDB2(bA, 0)
  LDA2(aA, 0)

  f32x4 acc[4][4];
#pragma unroll
  for (int mt = 0; mt < 4; mt++) {
    int obase = w * 64 + mt * 16 + q * 4;
    float b4[4];
#pragma unroll
    for (int r = 0; r < 4; r++) b4[r] = pw_b[obase + r];
#pragma unroll
    for (int nt = 0; nt < 4; nt++) {
      int p = p0 + nt * 16 + n;
#pragma unroll
      for (int r = 0; r < 4; r++) {
        size_t idx = ((size_t)b * O + obase + r) * HW + p;
        acc[mt][nt][r] = b4[r] + __builtin_nontemporal_load(&x[idx]);
      }
    }
  }

#pragma unroll
  for (int ks = 0; ks < 12; ks += 2) {
    if (ks + 1 < 12) { LDB2(bB, ks + 1) LDA2(aB, ks + 1) }
    STEP2(aA, bA)
    if (ks + 2 < 12) { LDB2(bA, ks + 2) LDA2(aA, ks + 2) }
    if (ks + 1 < 12) STEP2(aB, bB)
  }
#undef LDA2
#undef LDB2
#undef STEP2

#pragma unroll
  for (int mt = 0; mt < 4; mt++) {
    int obase = w * 64 + mt * 16 + q * 4;
#pragma unroll
    for (int nt = 0; nt < 4; nt++) {
      int p = p0 + nt * 16 + n;
#pragma unroll
      for (int r = 0; r < 4; r++) {
        size_t idx = ((size_t)b * O + obase + r) * HW + p;
        out[idx] = acc[mt][nt][r];
      }
    }
  }
}

// ---------------------------------------------------------------------------
extern "C" void kernel_launch(void* const* d_in, const int* in_sizes, int n_in,
                              void* d_out, int out_size, void* d_ws, size_t ws_size,
                              hipStream_t stream) {
  const float* x     = (const float*)d_in[0];
  const float* pw1_w = (const float*)d_in[1];
  const float* pw1_b = (const float*)d_in[2];
  const float* fc1_w = (const float*)d_in[3];
  const float* fc1_b = (const float*)d_in[4];
  const float* fc2_w = (const float*)d_in[5];
  const float* fc2_b = (const float*)d_in[6];
  const float* off_w = (const float*)d_in[7];
  const float* off_b = (const float*)d_in[8];
  const float* dw3   = (const float*)d_in[9];
  const float* dw5   = (const float*)d_in[10];
  const float* dw7   = (const float*)d_in[11];
  const float* pw_w  = (const float*)d_in[12];
  const float* pw_b  = (const float*)d_in[13];
  float* out = (float*)d_out;
  float* ws  = (float*)d_ws;

  kT<<<384, 256, 0, stream>>>(pw1_w, pw_w, ws);
  kAT<<<dim3(HW / 256, 32, B), 256, 0, stream>>>(x, ws);
  kB<<<B, 256, 0, stream>>>(pw1_w, pw1_b, fc1_w, fc1_b, fc2_w, fc2_b, ws);
  kCm<<<dim3(HW / 64, 1, B), 256, 0, stream>>>(pw1_b, ws);
  kD1<<<1, 256, 0, stream>>>(off_w, off_b, ws);
  kD2<<<84, 256, 0, stream>>>(dw3, dw5, dw7, ws);
  kEm<<<dim3(16, 16, B), 256, 0, stream>>>(ws, ws);
  kFm<<<dim3(HW / 64, 1, B), 256, 0, stream>>>(x, pw_b, ws, out);
}

// Round 8
// 551.803 us; speedup vs baseline: 1.1852x; 1.0258x over previous
//
#include <hip/hip_runtime.h>
#include <math.h>

// Problem constants
constexpr int B  = 8;
constexpr int C  = 256;   // Cin
constexpr int M  = 256;
constexpr int O  = 256;
constexpr int H  = 128;
constexpr int W  = 128;
constexpr int HW = H * W; // 16384
constexpr int K  = 128;   // top-k / kept channels

using f16   = _Float16;
using f16x2 = __attribute__((ext_vector_type(2))) _Float16;
using f16x8 = __attribute__((ext_vector_type(8))) _Float16;
using f32x4 = __attribute__((ext_vector_type(4))) float;

// Workspace layout (offsets in float units)
constexpr size_t WS_MEANX = 0;        // 2048
constexpr size_t WS_MASK  = 2048;     // 2048
constexpr size_t WS_G2    = 4096;     // 2048
constexpr size_t WS_OFF   = 6144;     // 48 (pad to 64)
constexpr size_t WS_WE3   = 6208;     // 9216
constexpr size_t WS_WE5   = 15424;    // 25600
constexpr size_t WS_WE7   = 41024;    // 50176
constexpr size_t WS_WT1G  = 91200;    // 65536 f16 (pw1_w fragment-linear)
constexpr size_t WS_WT2G  = 123968;   // 98304 f16 (pw_w[:, :384] fragment-linear)
constexpr size_t WS_SELH  = 173120;   // B*K*HW f16 = 8388608 float slots (33.5 MB)
// BIG region: union of xh (B*C*HW f16, dead after kCm) and yh2 (3*B*K*HW f16)
constexpr size_t WS_BIG   = 8561728;
// end = 33727552 floats = 134.91 MB (same proven footprint as before)

// ---------------------------------------------------------------------------
// Kernel T: fragment-linear f16 weight copies + zero meanx/gap2sum.
// NEW: also warm-read fc1_w/fc2_w into L3 (kB later runs with only 8 blocks
// and was pulling ~1.25 MB of cold weights at single-CU HBM latency).
// ---------------------------------------------------------------------------
__global__ __launch_bounds__(256) void kT(const float* __restrict__ pw1_w,
                                          const float* __restrict__ pw_w,
                                          const float* __restrict__ fc1_w,
                                          const float* __restrict__ fc2_w,
                                          float* __restrict__ ws) {
  f16* wt1g = (f16*)(ws + WS_WT1G);
  f16* wt2g = (f16*)(ws + WS_WT2G);
  int t = blockIdx.x * 256 + threadIdx.x;
  if (t < 65536) {
    int ks = t >> 13, fr = (t >> 9) & 15, l = (t >> 3) & 63, j = t & 7;
    int o = fr * 16 + (l & 15);
    int c = ks * 32 + ((l >> 4) << 3) + j;
    wt1g[t] = (f16)pw1_w[o * C + c];
  }
  if (t < 98304) {
    int ks = t >> 13, fr = (t >> 9) & 15, l = (t >> 3) & 63, j = t & 7;
    int o = fr * 16 + (l & 15);
    int cc = ks * 32 + ((l >> 4) << 3) + j;
    wt2g[t] = (f16)pw_w[(size_t)o * 768 + cc];
  }
  if (t < 2048) {
    ws[WS_MEANX + t] = 0.f;
    ws[WS_G2 + t]    = 0.f;
  }
  // L3 warm for kB: fc1_w (512x256) + fc2_w (256x512), 32768 float4 each.
  if (t < 32768) {
    float4 a = ((const float4*)fc1_w)[t];
    float4 c = ((const float4*)fc2_w)[t];
    float dead = a.x + a.y + a.z + a.w + c.x + c.y + c.z + c.w;
    asm volatile("" :: "v"(dead));  // keep reads live without storing
  }
}

// ---------------------------------------------------------------------------
// Kernel AT: read x once; per-channel means (atomic partials) and xh = f16 x
// in octet-interleaved layout xh[((b*32+ko)*HW + p)*8 + j], k = 8ko+j.
// ---------------------------------------------------------------------------
__global__ __launch_bounds__(256) void kAT(const float* __restrict__ x,
                                           float* __restrict__ ws) {
  float* meanx = ws + WS_MEANX;
  f16* xh      = (f16*)(ws + WS_BIG);
  int b = blockIdx.z, ko = blockIdx.y, p0 = blockIdx.x * 256;
  __shared__ float sx[8][256];
  int t = threadIdx.x;
  int c8 = t >> 5, pg = t & 31;
  const float* xp = x + (size_t)(b * 256 + ko * 8 + c8) * HW + p0 + pg * 8;
  float4 v0 = ((const float4*)xp)[0];
  float4 v1 = ((const float4*)xp)[1];
  *(float4*)&sx[c8][pg * 8]     = v0;
  *(float4*)&sx[c8][pg * 8 + 4] = v1;
  float s = v0.x + v0.y + v0.z + v0.w + v1.x + v1.y + v1.z + v1.w;
#pragma unroll
  for (int off = 16; off > 0; off >>= 1) s += __shfl_xor(s, off, 32);
  if (pg == 0) atomicAdd(&meanx[b * 256 + ko * 8 + c8], s * (1.f / HW));
  __syncthreads();
  f16x8 o;
#pragma unroll
  for (int j = 0; j < 8; j++) o[j] = (f16)sx[j][t];
  *(f16x8*)&xh[((size_t)(b * 32 + ko) * HW + p0 + t) * 8] = o;
}

// ---------------------------------------------------------------------------
// Kernel B: per-batch block; exact fp32 scoring path (unchanged).
// ---------------------------------------------------------------------------
__global__ __launch_bounds__(256) void kB(const float* __restrict__ pw1_w,
                                          const float* __restrict__ pw1_b,
                                          const float* __restrict__ fc1_w,
                                          const float* __restrict__ fc1_b,
                                          const float* __restrict__ fc2_w,
                                          const float* __restrict__ fc2_b,
                                          float* __restrict__ ws) {
  int b = blockIdx.x;
  const float* meanx = ws + WS_MEANX + b * C;
  float* maskg = ws + WS_MASK;
  __shared__ float s_gap[M];
  __shared__ float s_hid[512];
  __shared__ float s_sc[M];
  int t = threadIdx.x;
  int lane = t & 63, wv = t >> 6;

  float4 mx = ((const float4*)meanx)[lane];
  for (int o0 = wv * 64; o0 < wv * 64 + 64; o0 += 4) {
    float s[4];
#pragma unroll
    for (int j = 0; j < 4; j++) {
      float4 w = ((const float4*)(pw1_w + (size_t)(o0 + j) * C))[lane];
      s[j] = mx.x * w.x + mx.y * w.y + mx.z * w.z + mx.w * w.w;
    }
#pragma unroll
    for (int off = 32; off > 0; off >>= 1)
#pragma unroll
      for (int j = 0; j < 4; j++) s[j] += __shfl_xor(s[j], off, 64);
    if (lane == 0) {
#pragma unroll
      for (int j = 0; j < 4; j++) s_gap[o0 + j] = s[j] + pw1_b[o0 + j];
    }
  }
  __syncthreads();

  float4 g4 = ((const float4*)s_gap)[lane];
  for (int j0 = wv * 128; j0 < wv * 128 + 128; j0 += 4) {
    float s[4];
#pragma unroll
    for (int j = 0; j < 4; j++) {
      float4 w = ((const float4*)(fc1_w + (size_t)(j0 + j) * M))[lane];
      s[j] = g4.x * w.x + g4.y * w.y + g4.z * w.z + g4.w * w.w;
    }
#pragma unroll
    for (int off = 32; off > 0; off >>= 1)
#pragma unroll
      for (int j = 0; j < 4; j++) s[j] += __shfl_xor(s[j], off, 64);
    if (lane == 0) {
#pragma unroll
      for (int j = 0; j < 4; j++) {
        float v = s[j] + fc1_b[j0 + j];
        s_hid[j0 + j] = v > 0.f ? v : 0.f;
      }
    }
  }
  __syncthreads();

  float4 h0 = ((const float4*)s_hid)[lane];
  float4 h1 = ((const float4*)s_hid)[lane + 64];
  for (int o0 = wv * 64; o0 < wv * 64 + 64; o0 += 4) {
    float s[4];
#pragma unroll
    for (int j = 0; j < 4; j++) {
      const float4* wr = (const float4*)(fc2_w + (size_t)(o0 + j) * 512);
      float4 w0 = wr[lane];
      float4 w1 = wr[lane + 64];
      s[j] = h0.x * w0.x + h0.y * w0.y + h0.z * w0.z + h0.w * w0.w +
             h1.x * w1.x + h1.y * w1.y + h1.z * w1.z + h1.w * w1.w;
    }
#pragma unroll
    for (int off = 32; off > 0; off >>= 1)
#pragma unroll
      for (int j = 0; j < 4; j++) s[j] += __shfl_xor(s[j], off, 64);
    if (lane == 0) {
#pragma unroll
      for (int j = 0; j < 4; j++) {
        float v = s[j] + fc2_b[o0 + j];
        s_sc[o0 + j] = 1.f / (1.f + expf(-v));
      }
    }
  }
  __syncthreads();

  {
    int j = t;
    float sj = s_sc[j];
    int cnt = 0;
    for (int m = 0; m < M; m++) {
      float sm = s_sc[m];
      cnt += (sm > sj) || (sm == sj && m < j);
    }
    maskg[b * M + j] = (cnt < K) ? 1.f : 0.f;
  }
}

// ---------------------------------------------------------------------------
// Kernel Cm: h = relu(pw1(x)) via f16 MFMA. Barrier-free, LDS-free, 64-px
// blocks. B double-buffered (L3-latency long pole); A loaded per-step into a
// single temp (L2-resident panel, ~200cyc, covered by MFMA+TLP) — saves
// ~32 VGPRs vs R7 for 4 waves/SIMD instead of 3.
// ---------------------------------------------------------------------------
__global__ __launch_bounds__(256) void kCm(const float* __restrict__ pw1_b,
                                           float* __restrict__ ws) {
  const f16* wt1g = (const f16*)(ws + WS_WT1G);
  const f16* xh   = (const f16*)(ws + WS_BIG);
  float* gap2sum  = ws + WS_G2;
  f16* selh       = (f16*)(ws + WS_SELH);
  int b  = blockIdx.z;
  int p0 = blockIdx.x * 64;

  int t = threadIdx.x, l = t & 63, w = t >> 6;
  int q = l >> 4, n = l & 15;

  const f16* bbase = xh + (size_t)(b * 32 + q) * (HW * 8) + (size_t)(p0 + n) * 8;
  const f16* abase = wt1g + (size_t)(w * 4) * 512 + (size_t)l * 8;

#define LDA1(dst, ks)                                                          \
  _Pragma("unroll") for (int mt = 0; mt < 4; mt++)                             \
      dst[mt] = *(const f16x8*)(abase + (size_t)((ks) * 16 + mt) * 512);
#define LDB1(dst, ks)                                                          \
  _Pragma("unroll") for (int nt = 0; nt < 4; nt++)                             \
      dst[nt] = *(const f16x8*)(bbase + (size_t)(ks) * (4 * HW * 8) + nt * 128);
#define STEP1(af, bf)                                                          \
  _Pragma("unroll") for (int mt = 0; mt < 4; mt++)                             \
      _Pragma("unroll") for (int nt = 0; nt < 4; nt++)                         \
          acc[mt][nt] = __builtin_amdgcn_mfma_f32_16x16x32_f16(                \
              af[mt], bf[nt], acc[mt][nt], 0, 0, 0);

  f16x8 bA[4], bB[4], aT[4];
  LDB1(bA, 0)

  f32x4 acc[4][4];
#pragma unroll
  for (int mt = 0; mt < 4; mt++) {
    int obase = w * 64 + mt * 16 + q * 4;
#pragma unroll
    for (int nt = 0; nt < 4; nt++)
#pragma unroll
      for (int r = 0; r < 4; r++) acc[mt][nt][r] = pw1_b[obase + r];
  }

#pragma unroll
  for (int ks = 0; ks < 8; ks += 2) {
    if (ks + 1 < 8) LDB1(bB, ks + 1)
    LDA1(aT, ks)
    STEP1(aT, bA)
    if (ks + 2 < 8) LDB1(bA, ks + 2)
    if (ks + 1 < 8) { LDA1(aT, ks + 1) STEP1(aT, bB) }
  }
#undef LDA1
#undef LDB1
#undef STEP1

  // Epilogue: relu; sel f16 store (o<128); gap2sum partial sums
#pragma unroll
  for (int mt = 0; mt < 4; mt++) {
    float rsum[4] = {0.f, 0.f, 0.f, 0.f};
    int obase = w * 64 + mt * 16 + q * 4;
#pragma unroll
    for (int nt = 0; nt < 4; nt++) {
      int p = p0 + nt * 16 + n;
#pragma unroll
      for (int r = 0; r < 4; r++) {
        float h = acc[mt][nt][r];
        h = h > 0.f ? h : 0.f;
        rsum[r] += h;
        int o = obase + r;
        if (o < K) selh[((size_t)(b * K + o)) * HW + p] = (f16)h;
      }
    }
#pragma unroll
    for (int off = 1; off < 16; off <<= 1)
#pragma unroll
      for (int r = 0; r < 4; r++) rsum[r] += __shfl_xor(rsum[r], off, 64);
    if (n == 0) {
#pragma unroll
      for (int r = 0; r < 4; r++)
        atomicAdd(&gap2sum[b * M + obase + r], rsum[r]);
    }
  }
}

// ---------------------------------------------------------------------------
// Kernel D1 (1 block): offsets from gap2; emit per-(b,branch) scale/shift.
// ---------------------------------------------------------------------------
__global__ __launch_bounds__(256) void kD1(const float* __restrict__ off_w,
                                           const float* __restrict__ off_b,
                                           float* __restrict__ ws) {
  const float* gap2sum = ws + WS_G2;
  float* offv = ws + WS_OFF;  // [0..23]=scale(b*3+i), [24..47]=shift
  __shared__ float s_off[48];
  int t = threadIdx.x;
  int lane = t & 63, wv = t >> 6;
  for (int id = wv; id < 48; id += 4) {
    int b = id / 6, j = id % 6;
    float4 g = ((const float4*)(gap2sum + b * M))[lane];
    float4 w = ((const float4*)(off_w + (size_t)j * M))[lane];
    float s = (g.x * w.x + g.y * w.y + g.z * w.z + g.w * w.w) * (1.f / HW);
#pragma unroll
    for (int off = 32; off > 0; off >>= 1) s += __shfl_xor(s, off, 64);
    if (lane == 0) s_off[id] = tanhf(s + off_b[j]);
  }
  __syncthreads();
  if (t < 24) {
    int b = t / 3, i = t % 3;
    offv[t]      = 1.f + 1.f / (1.f + expf(-s_off[b * 6 + 2 * i]));
    offv[24 + t] = tanhf(s_off[b * 6 + 2 * i + 1]);
  }
}

// ---------------------------------------------------------------------------
// Kernel D2: effective depthwise weights, with top-k mask folded in.
// ---------------------------------------------------------------------------
__global__ __launch_bounds__(256) void kD2(const float* __restrict__ dw3,
                                           const float* __restrict__ dw5,
                                           const float* __restrict__ dw7,
                                           float* __restrict__ ws) {
  const float* offv  = ws + WS_OFF;
  const float* maskg = ws + WS_MASK;
  float* wE3 = ws + WS_WE3;
  float* wE5 = ws + WS_WE5;
  float* wE7 = ws + WS_WE7;
  int tid = blockIdx.x * 256 + threadIdx.x;
  int stride = gridDim.x * 256;
  for (int i = tid; i < B * K * 9; i += stride) {
    int b = i / (K * 9), rem = i % (K * 9), c = rem / 9;
    wE3[i] = (dw3[rem] * offv[b * 3 + 0] + offv[24 + b * 3 + 0]) * maskg[b * M + c];
  }
  for (int i = tid; i < B * K * 25; i += stride) {
    int b = i / (K * 25), rem = i % (K * 25), c = rem / 25;
    wE5[i] = (dw5[rem] * offv[b * 3 + 1] + offv[24 + b * 3 + 1]) * maskg[b * M + c];
  }
  for (int i = tid; i < B * K * 49; i += stride) {
    int b = i / (K * 49), rem = i % (K * 49), c = rem / 49;
    wE7[i] = (dw7[rem] * offv[b * 3 + 2] + offv[24 + b * 3 + 2]) * maskg[b * M + c];
  }
}

// ---------------------------------------------------------------------------
// Kernel Em: merged depthwise conv. f16 halo in LDS; compute = f16x2 LDS
// reads -> cvt -> fp32 fma. Vectorized fill: halo row origin c0-8 is
// 8-aligned -> pure f16x8 chunks. Plane stride 1768 f16 (884 dw % 32 = 20).
// Block: 256 thr = 8 ch x 32 col-pairs; 16 rows x 64 cols x 8 ch per block.
// ---------------------------------------------------------------------------
__global__ __launch_bounds__(256) void kEm(const float* __restrict__ ws_ro,
                                           float* __restrict__ ws) {
  constexpr int SP = 1768;  // f16 per channel plane (22 rows x 80 + pad)
  __shared__ f16 sm[8 * SP];  // 28288 B
  const f16* selh = (const f16*)(ws_ro + WS_SELH);
  f16* yh2        = (f16*)(ws + WS_BIG);
  int bx = blockIdx.x;
  int slab = bx >> 1, chalf = bx & 1;
  int ko = blockIdx.y, b = blockIdx.z;
  int r0 = slab * 16, c0 = chalf * 64;

  // Fill: per (ch, row rr of 22, chunk of 10): one f16x8 from global or zeros.
  // LDS row col L corresponds to global col c0 - 8 + L.
  for (int i = threadIdx.x; i < 8 * 220; i += 256) {
    int chn = i / 220, rem = i - chn * 220;
    int rr = rem / 10, chunk = rem - rr * 10;
    int gy = r0 - 3 + rr, g0 = c0 - 8 + chunk * 8;
    f16x8 v = {};
    if (gy >= 0 && gy < H && g0 >= 0 && g0 < W)
      v = *(const f16x8*)&selh[(size_t)(b * 128 + ko * 8 + chn) * HW + gy * W + g0];
    *(f16x8*)&sm[chn * SP + rr * 80 + chunk * 8] = v;
  }
  __syncthreads();

  int t = threadIdx.x;
  int ch = t & 7, cp = t >> 3;  // channel 0..7, col-pair 0..31
  int cglob = c0 + cp * 2;

  // Tap f16-index within the vv window: even col: (8-P)+dx-2*SOFF,
  // odd col: (9-P)+dx-2*SOFF. (KS,NW,SOFF) = (3,3,3),(5,3,3),(7,5,2).
#define CONV_BRANCH(KS, BR, WSOFF, NW, SOFF)                                   \
  {                                                                            \
    constexpr int P = (KS - 1) / 2;                                            \
    const float* wp = ws_ro + WSOFF + (size_t)(b * 128 + ko * 8 + ch) * (KS*KS); \
    float w[KS * KS];                                                          \
    _Pragma("unroll") for (int i = 0; i < KS * KS; i++) w[i] = wp[i];          \
    float a0[16], a1[16];                                                      \
    _Pragma("unroll") for (int r = 0; r < 16; r++) { a0[r] = 0.f; a1[r] = 0.f; } \
    _Pragma("unroll") for (int iy = 0; iy < 16 + 2 * P; iy++) {                \
      int hr = iy + (3 - P);                                                   \
      const f16x2* rowp = (const f16x2*)(sm + ch * SP + hr * 80);              \
      float vv[2 * NW];                                                        \
      _Pragma("unroll") for (int u = 0; u < NW; u++) {                         \
        f16x2 pr = rowp[cp + SOFF + u];                                        \
        vv[2 * u]     = (float)pr[0];                                          \
        vv[2 * u + 1] = (float)pr[1];                                          \
      }                                                                        \
      _Pragma("unroll") for (int rr = 0; rr < 16; rr++) {                      \
        int dy = iy - rr;                                                      \
        if (dy >= 0 && dy < KS) {                                              \
          _Pragma("unroll") for (int dx = 0; dx < KS; dx++) {                  \
            int m = (8 - P) + dx - 2 * SOFF;                                   \
            a0[rr] += vv[m]     * w[dy * KS + dx];                             \
            a1[rr] += vv[m + 1] * w[dy * KS + dx];                             \
          }                                                                    \
        }                                                                      \
      }                                                                        \
    }                                                                          \
    f16* op = yh2 + (size_t)(b * 48 + BR * 16 + ko) * HW * 8;                  \
    _Pragma("unroll") for (int rr = 0; rr < 16; rr++) {                        \
      size_t pa = ((size_t)(r0 + rr) * W + cglob) * 8 + ch;                    \
      op[pa]     = (f16)a0[rr];                                                \
      op[pa + 8] = (f16)a1[rr];                                                \
    }                                                                          \
  }

  CONV_BRANCH(3, 0, WS_WE3, 3, 3)
  CONV_BRANCH(5, 1, WS_WE5, 3, 3)
  CONV_BRANCH(7, 2, WS_WE7, 5, 2)
#undef CONV_BRANCH
}

// ---------------------------------------------------------------------------
// Kernel Fm: merged final pointwise, f16 MFMA, K=384. Barrier-free, LDS-free,
// 64-px blocks. B double-buffered; A per-step single temp (L2-hot). Residual
// + bias folded into accumulator init; x loads nontemporal.
// ---------------------------------------------------------------------------
__global__ __launch_bounds__(256) void kFm(const float* __restrict__ x,
                                           const float* __restrict__ pw_b,
                                           const float* __restrict__ ws,
                                           float* __restrict__ out) {
  const f16* wt2g = (const f16*)(ws + WS_WT2G);
  const f16* yh2  = (const f16*)(ws + WS_BIG);
  int b  = blockIdx.z;
  int p0 = blockIdx.x * 64;

  int t = threadIdx.x, l = t & 63, w = t >> 6;
  int q = l >> 4, n = l & 15;

  const f16* bbase = yh2 + (size_t)(b * 48 + q) * (HW * 8) + (size_t)(p0 + n) * 8;
  const f16* abase = wt2g + (size_t)(w * 4) * 512 + (size_t)l * 8;

#define LDA2(dst, ks)                                                          \
  _Pragma("unroll") for (int mt = 0; mt < 4; mt++)                             \
      dst[mt] = *(const f16x8*)(abase + (size_t)((ks) * 16 + mt) * 512);
#define LDB2(dst, ks)                                                          \
  _Pragma("unroll") for (int nt = 0; nt < 4; nt++)                             \
      dst[nt] = *(const f16x8*)(bbase + (size_t)(ks) * (4 * HW * 8) + nt * 128);
#define STEP2(af, bf)                                                          \
  _Pragma("unroll") for (int mt = 0; mt < 4; mt++)                             \
      _Pragma("unroll") for (int nt = 0; nt < 4; nt++)                         \
          acc[mt][nt] = __builtin_amdgcn_mfma_f32_16x16x32_f16(                \
              af[mt], bf[nt], acc[mt][nt], 0, 0, 0);

  f16x8 bA[4], bB[4], aT[4];
  LDB2(bA, 0)

  f32x4 acc[4][4];
#pragma unroll
  for (int mt = 0; mt < 4; mt++) {
    int obase = w * 64 + mt * 16 + q * 4;
    float b4[4];
#pragma unroll
    for (int r = 0; r < 4; r++) b4[r] = pw_b[obase + r];
#pragma unroll
    for (int nt = 0; nt < 4; nt++) {
      int p = p0 + nt * 16 + n;
#pragma unroll
      for (int r = 0; r < 4; r++) {
        size_t idx = ((size_t)b * O + obase + r) * HW + p;
        acc[mt][nt][r] = b4[r] + __builtin_nontemporal_load(&x[idx]);
      }
    }
  }

#pragma unroll
  for (int ks = 0; ks < 12; ks += 2) {
    if (ks + 1 < 12) LDB2(bB, ks + 1)
    LDA2(aT, ks)
    STEP2(aT, bA)
    if (ks + 2 < 12) LDB2(bA, ks + 2)
    if (ks + 1 < 12) { LDA2(aT, ks + 1) STEP2(aT, bB) }
  }
#undef LDA2
#undef LDB2
#undef STEP2

#pragma unroll
  for (int mt = 0; mt < 4; mt++) {
    int obase = w * 64 + mt * 16 + q * 4;
#pragma unroll
    for (int nt = 0; nt < 4; nt++) {
      int p = p0 + nt * 16 + n;
#pragma unroll
      for (int r = 0; r < 4; r++) {
        size_t idx = ((size_t)b * O + obase + r) * HW + p;
        out[idx] = acc[mt][nt][r];
      }
    }
  }
}

// ---------------------------------------------------------------------------
extern "C" void kernel_launch(void* const* d_in, const int* in_sizes, int n_in,
                              void* d_out, int out_size, void* d_ws, size_t ws_size,
                              hipStream_t stream) {
  const float* x     = (const float*)d_in[0];
  const float* pw1_w = (const float*)d_in[1];
  const float* pw1_b = (const float*)d_in[2];
  const float* fc1_w = (const float*)d_in[3];
  const float* fc1_b = (const float*)d_in[4];
  const float* fc2_w = (const float*)d_in[5];
  const float* fc2_b = (const float*)d_in[6];
  const float* off_w = (const float*)d_in[7];
  const float* off_b = (const float*)d_in[8];
  const float* dw3   = (const float*)d_in[9];
  const float* dw5   = (const float*)d_in[10];
  const float* dw7   = (const float*)d_in[11];
  const float* pw_w  = (const float*)d_in[12];
  const float* pw_b  = (const float*)d_in[13];
  float* out = (float*)d_out;
  float* ws  = (float*)d_ws;

  kT<<<384, 256, 0, stream>>>(pw1_w, pw_w, fc1_w, fc2_w, ws);
  kAT<<<dim3(HW / 256, 32, B), 256, 0, stream>>>(x, ws);
  kB<<<B, 256, 0, stream>>>(pw1_w, pw1_b, fc1_w, fc1_b, fc2_w, fc2_b, ws);
  kCm<<<dim3(HW / 64, 1, B), 256, 0, stream>>>(pw1_b, ws);
  kD1<<<1, 256, 0, stream>>>(off_w, off_b, ws);
  kD2<<<84, 256, 0, stream>>>(dw3, dw5, dw7, ws);
  kEm<<<dim3(16, 16, B), 256, 0, stream>>>(ws, ws);
  kFm<<<dim3(HW / 64, 1, B), 256, 0, stream>>>(x, pw_b, ws, out);
}